// Round 1
// baseline (29327.542 us; speedup 1.0000x reference)
//
#include <hip/hip_runtime.h>
#include <math.h>

// RITS recurrent imputation. B=256, T=100, F=256, H=512.
// Round 3: the recurrence is independent per batch row (only the loss is a
// global, associative reduction). So: NO grid syncs at all. 16 wgs x 512
// threads; each wg owns 16 batch rows and runs the whole T-loop privately
// with LDS state + 4 __syncthreads per t. Weights stream from L2/LLC as
// MFMA B-fragments. Numerics (bf16 rounding points) identical to round 2.

#define T_ 100

typedef unsigned short ushortT;
typedef __attribute__((ext_vector_type(8))) short short8;
typedef __attribute__((ext_vector_type(4))) float f32x4;

// ---- workspace byte offsets ----
#define OB_NUM2   2097152u    // fp32 [16] per-wg loss partials
#define OB_DEN    2122752u    // fp32 [128] per-t mask sums
#define OB_BIASP  2123776u    // fp32 [2048] packed b_ih+b_hh
#define OB_BA     2131968u    // bf16 W_hist [256*512]
#define OB_BB     2394112u    // bf16 Wf masked [256*256]
#define OB_BC     2525184u    // bf16 packed [2048*1024] = [wihp|whhp]
#define OB_GH     19826688u   // bf16 gamma_h [25600*512]
#define OB_AL     46041088u   // bf16 alpha [25600*256]

__device__ __forceinline__ float sigm(float x) { return 1.0f / (1.0f + expf(-x)); }

__device__ __forceinline__ ushortT f2bf(float f) {
    union { float f; unsigned u; } v; v.f = f;
    unsigned r = v.u + 0x7fffu + ((v.u >> 16) & 1u);   // RNE
    return (ushortT)(r >> 16);
}
__device__ __forceinline__ float bf2f(ushortT h) {
    union { unsigned u; float f; } v; v.u = ((unsigned)h) << 16; return v.f;
}

// ---------------- prep kernels (unchanged numerics) ----------------

__global__ __launch_bounds__(256) void k_prep2(const float* __restrict__ W_ih,
                                               const float* __restrict__ W_hh,
                                               const float* __restrict__ b_ih,
                                               const float* __restrict__ b_hh,
                                               const float* __restrict__ W_hist,
                                               const float* __restrict__ W_feat,
                                               unsigned char* wsb) {
    ushortT* Bc = (ushortT*)(wsb + OB_BC);
    ushortT* Ba = (ushortT*)(wsb + OB_BA);
    ushortT* Bb = (ushortT*)(wsb + OB_BB);
    float* biasp = (float*)(wsb + OB_BIASP);
    int n = blockIdx.x;                  // packed row, n = 4*j + g
    int j = n >> 2, g = n & 3;
    int src = g * 512 + j;
    for (int k = threadIdx.x; k < 512; k += 256) {
        Bc[(size_t)n * 1024 + k]       = f2bf(W_ih[(size_t)src * 512 + k]);
        Bc[(size_t)n * 1024 + 512 + k] = f2bf(W_hh[(size_t)src * 512 + k]);
        if (n < 256) {
            Ba[(size_t)n * 512 + k] = f2bf(W_hist[(size_t)n * 512 + k]);
            if (k < 256) Bb[(size_t)n * 256 + k] = (k == n) ? 0 : f2bf(W_feat[(size_t)n * 256 + k]);
        }
    }
    if (threadIdx.x == 0) biasp[n] = b_ih[src] + b_hh[src];
}

__global__ __launch_bounds__(256) void k_den(const float* __restrict__ masks, unsigned char* wsb) {
    __shared__ float red[256];
    float* den = (float*)(wsb + OB_DEN);
    int t = blockIdx.x;
    float s = 0.0f;
    for (int idx = threadIdx.x; idx < 256 * 256; idx += 256) {
        int b = idx >> 8, f = idx & 255;
        s += masks[((size_t)b * T_ + t) * 256 + f];
    }
    red[threadIdx.x] = s; __syncthreads();
    for (int st = 128; st > 0; st >>= 1) { if (threadIdx.x < st) red[threadIdx.x] += red[threadIdx.x + st]; __syncthreads(); }
    if (threadIdx.x == 0) den[t] = red[0];
}

// gamma_h: [25600,512] = exp(-relu(D @ W_td_h.T + b)), K=256 (fp32 tile GEMM)
__global__ __launch_bounds__(256) void k_gamma_h(const float* __restrict__ deltas,
                                                 const float* __restrict__ W,
                                                 const float* __restrict__ bias,
                                                 unsigned char* wsb) {
    ushortT* gh = (ushortT*)(wsb + OB_GH);
    __shared__ float As[16][65];
    __shared__ float Bs[16][65];
    int tid = threadIdx.x;
    int tx = tid & 15, ty = tid >> 4;
    int mb = blockIdx.x * 64, nb = blockIdx.y * 64;
    int lr = tid >> 2, lk = (tid & 3) * 4;
    float acc[4][4] = {};
    for (int k0 = 0; k0 < 256; k0 += 16) {
        float4 a = *(const float4*)(deltas + (size_t)(mb + lr) * 256 + k0 + lk);
        float4 b = *(const float4*)(W + (size_t)(nb + lr) * 256 + k0 + lk);
        As[lk + 0][lr] = a.x; As[lk + 1][lr] = a.y; As[lk + 2][lr] = a.z; As[lk + 3][lr] = a.w;
        Bs[lk + 0][lr] = b.x; Bs[lk + 1][lr] = b.y; Bs[lk + 2][lr] = b.z; Bs[lk + 3][lr] = b.w;
        __syncthreads();
#pragma unroll
        for (int kk = 0; kk < 16; kk++) {
            float av[4], bv[4];
#pragma unroll
            for (int i = 0; i < 4; i++) av[i] = As[kk][ty * 4 + i];
#pragma unroll
            for (int j = 0; j < 4; j++) bv[j] = Bs[kk][tx * 4 + j];
#pragma unroll
            for (int i = 0; i < 4; i++)
#pragma unroll
                for (int j = 0; j < 4; j++) acc[i][j] = fmaf(av[i], bv[j], acc[i][j]);
        }
        __syncthreads();
    }
#pragma unroll
    for (int i = 0; i < 4; i++) {
        int r = mb + ty * 4 + i;
#pragma unroll
        for (int j = 0; j < 4; j++) {
            int n = nb + tx * 4 + j;
            float v = acc[i][j] + bias[n];
            gh[(size_t)r * 512 + n] = f2bf(expf(-fmaxf(v, 0.0f)));
        }
    }
}

// alpha: [25600,256] = sigmoid([gamma_x|m] @ W_comb.T + b), K=512
__global__ __launch_bounds__(256) void k_alpha(const float* __restrict__ deltas,
                                               const float* __restrict__ masks,
                                               const float* __restrict__ Wtdx,
                                               const float* __restrict__ btdx,
                                               const float* __restrict__ Wc,
                                               const float* __restrict__ bc,
                                               unsigned char* wsb) {
    ushortT* al = (ushortT*)(wsb + OB_AL);
    __shared__ float As[16][65];
    __shared__ float Bs[16][65];
    int tid = threadIdx.x;
    int tx = tid & 15, ty = tid >> 4;
    int mb = blockIdx.x * 64, nb = blockIdx.y * 64;
    int lr = tid >> 2, lk = (tid & 3) * 4;
    float acc[4][4] = {};
    for (int k0 = 0; k0 < 512; k0 += 16) {
        int kg = k0 + lk;
        float4 a;
        if (kg < 256) {
            float4 d4 = *(const float4*)(deltas + (size_t)(mb + lr) * 256 + kg);
            a.x = expf(-fmaxf(d4.x * Wtdx[(size_t)(kg + 0) * 257] + btdx[kg + 0], 0.0f));
            a.y = expf(-fmaxf(d4.y * Wtdx[(size_t)(kg + 1) * 257] + btdx[kg + 1], 0.0f));
            a.z = expf(-fmaxf(d4.z * Wtdx[(size_t)(kg + 2) * 257] + btdx[kg + 2], 0.0f));
            a.w = expf(-fmaxf(d4.w * Wtdx[(size_t)(kg + 3) * 257] + btdx[kg + 3], 0.0f));
        } else {
            a = *(const float4*)(masks + (size_t)(mb + lr) * 256 + (kg - 256));
        }
        float4 b = *(const float4*)(Wc + (size_t)(nb + lr) * 512 + kg);
        As[lk + 0][lr] = a.x; As[lk + 1][lr] = a.y; As[lk + 2][lr] = a.z; As[lk + 3][lr] = a.w;
        Bs[lk + 0][lr] = b.x; Bs[lk + 1][lr] = b.y; Bs[lk + 2][lr] = b.z; Bs[lk + 3][lr] = b.w;
        __syncthreads();
#pragma unroll
        for (int kk = 0; kk < 16; kk++) {
            float av[4], bv[4];
#pragma unroll
            for (int i = 0; i < 4; i++) av[i] = As[kk][ty * 4 + i];
#pragma unroll
            for (int j = 0; j < 4; j++) bv[j] = Bs[kk][tx * 4 + j];
#pragma unroll
            for (int i = 0; i < 4; i++)
#pragma unroll
                for (int j = 0; j < 4; j++) acc[i][j] = fmaf(av[i], bv[j], acc[i][j]);
        }
        __syncthreads();
    }
#pragma unroll
    for (int i = 0; i < 4; i++) {
        int r = mb + ty * 4 + i;
#pragma unroll
        for (int j = 0; j < 4; j++) {
            int n = nb + tx * 4 + j;
            al[(size_t)r * 256 + n] = f2bf(sigm(acc[i][j] + bc[n]));
        }
    }
}

// ---------------- sync-free row-parallel T-loop ----------------
// wg = 16 rows of the batch; 8 waves. Per t:
//   A: x_h[16,256] = hd @ Ba^T      (wave w -> cols w*32..w*32+31, K=512)
//   B: z_h[16,256] = xcb @ Bb^T     (same col split, K=256)
//   C: gates[16,2048] = [ccb|mtb|hd] @ Bc^T (wave w -> cols w*256.., K=1024)
//      + gate exchange (per-wave LDS scratch) + LSTM update (c in registers)
// 4 __syncthreads per t; no inter-wg communication except final loss partial.

__global__ __launch_bounds__(512, 1) void k_rows(const float* __restrict__ values,
                                                 const float* __restrict__ masks,
                                                 const float* __restrict__ b_hist,
                                                 const float* __restrict__ b_feat,
                                                 float* __restrict__ out,
                                                 unsigned char* __restrict__ wsb) {
    const ushortT* Ba = (const ushortT*)(wsb + OB_BA);
    const ushortT* Bb = (const ushortT*)(wsb + OB_BB);
    const ushortT* Bc = (const ushortT*)(wsb + OB_BC);
    const ushortT* gh = (const ushortT*)(wsb + OB_GH);
    const ushortT* al = (const ushortT*)(wsb + OB_AL);
    const float* biasp = (const float*)(wsb + OB_BIASP);
    const float* den = (const float*)(wsb + OB_DEN);
    float* partials = (float*)(wsb + OB_NUM2);

    __shared__ ushortT hd[16 * 520];     // bf16 decayed h, stride 520 breaks bank conflicts
    __shared__ ushortT xcb[16 * 264];    // bf16 x_c
    __shared__ ushortT mtb[16 * 264];    // bf16 m
    __shared__ ushortT ccb[16 * 264];    // bf16 c_c
    __shared__ float   xhs[16 * 260];    // fp32 x_h; phase-C epilogue aliases as gate scratch
    __shared__ float   red[8];
    // total 58,656 B static LDS

    const int tid = threadIdx.x;
    const int w = tid >> 6, lane = tid & 63, quad = lane >> 4, l16 = lane & 15;
    const int b0 = blockIdx.x * 16;

    for (int i = tid; i < 16 * 520; i += 512) hd[i] = 0;   // h0 = 0

    float creg[16];                                        // c state, fixed cell/thread
#pragma unroll
    for (int i = 0; i < 16; ++i) creg[i] = 0.f;

    // t-invariant per-thread addresses / scalars
    const int nAB0 = w * 32 + l16;                         // phase A/B col (+c2*16)
    const ushortT* bA0 = Ba + (size_t)nAB0 * 512 + quad * 8;
    const ushortT* bB0 = Bb + (size_t)nAB0 * 256 + quad * 8;
    const ushortT* bC0 = Bc + (size_t)(w * 256 + l16) * 1024 + quad * 8;
    float bpl[16];
#pragma unroll
    for (int ct = 0; ct < 16; ++ct) bpl[ct] = biasp[w * 256 + ct * 16 + l16];
    float bhv[2], bfv[2];
#pragma unroll
    for (int c2 = 0; c2 < 2; ++c2) { bhv[c2] = b_hist[nAB0 + c2 * 16]; bfv[c2] = b_feat[nAB0 + c2 * 16]; }
    const int rme = lane >> 2, jj = lane & 3;              // phase-C epilogue cell (row, j%4)
    const int gb = b0 + rme;

    float* scr = xhs + w * 320;                            // [16][20] per-wave gate scratch

    float lacc = 0.f;
    __syncthreads();

#pragma unroll 1
    for (int t = 0; t < T_; ++t) {
        const float dent = den[t] + 1e-9f;

        // prefetch this wave's per-cell globals (hidden under MFMA)
        float xr[8], mr[8], alr[8];
        ushortT ghr[16];
#pragma unroll
        for (int c2 = 0; c2 < 2; ++c2)
#pragma unroll
            for (int r4 = 0; r4 < 4; ++r4) {
                const int r = quad * 4 + r4, n = nAB0 + c2 * 16;
                const size_t idx = ((size_t)(b0 + r) * T_ + t) * 256 + n;
                xr[c2 * 4 + r4] = values[idx];
                mr[c2 * 4 + r4] = masks[idx];
                alr[c2 * 4 + r4] = bf2f(al[idx]);
            }
        if (t < T_ - 1) {
#pragma unroll
            for (int ct = 0; ct < 16; ++ct)
                ghr[ct] = gh[((size_t)gb * T_ + t + 1) * 512 + (w * 64 + ct * 4 + jj)];
        }

        // ---- phase A: x_h = hd @ Ba^T ----
        f32x4 accA0 = {0.f, 0.f, 0.f, 0.f}, accA1 = {0.f, 0.f, 0.f, 0.f};
#pragma unroll
        for (int kc = 0; kc < 16; ++kc) {
            short8 a = *(const short8*)&hd[l16 * 520 + kc * 32 + quad * 8];
            short8 g0 = *(const short8*)(bA0 + kc * 32);
            short8 g1 = *(const short8*)(bA0 + 8192 + kc * 32);
            accA0 = __builtin_amdgcn_mfma_f32_16x16x32_bf16(a, g0, accA0, 0, 0, 0);
            accA1 = __builtin_amdgcn_mfma_f32_16x16x32_bf16(a, g1, accA1, 0, 0, 0);
        }
        float pt = 0.f;
#pragma unroll
        for (int c2 = 0; c2 < 2; ++c2) {
            const int n = nAB0 + c2 * 16;
#pragma unroll
            for (int r4 = 0; r4 < 4; ++r4) {
                const int r = quad * 4 + r4;
                const float x = xr[c2 * 4 + r4], m = mr[c2 * 4 + r4];
                const float v = (c2 ? accA1[r4] : accA0[r4]) + bhv[c2];
                xhs[r * 260 + n] = v;
                xcb[r * 264 + n] = f2bf(m * x + (1.f - m) * v);
                mtb[r * 264 + n] = f2bf(m);
                pt += fabsf(v - x) * m;
            }
        }
        __syncthreads();   // (1) xcb/mtb/xhs visible

        // ---- phase B: z_h = x_c @ Bb^T + epilogue ----
        f32x4 accB0 = {0.f, 0.f, 0.f, 0.f}, accB1 = {0.f, 0.f, 0.f, 0.f};
        {
            short8 af[8];
#pragma unroll
            for (int kc = 0; kc < 8; ++kc)
                af[kc] = *(const short8*)&xcb[l16 * 264 + kc * 32 + quad * 8];
#pragma unroll
            for (int kc = 0; kc < 8; ++kc) {
                short8 g0 = *(const short8*)(bB0 + kc * 32);
                short8 g1 = *(const short8*)(bB0 + 4096 + kc * 32);
                accB0 = __builtin_amdgcn_mfma_f32_16x16x32_bf16(af[kc], g0, accB0, 0, 0, 0);
                accB1 = __builtin_amdgcn_mfma_f32_16x16x32_bf16(af[kc], g1, accB1, 0, 0, 0);
            }
        }
#pragma unroll
        for (int c2 = 0; c2 < 2; ++c2) {
            const int n = nAB0 + c2 * 16;
#pragma unroll
            for (int r4 = 0; r4 < 4; ++r4) {
                const int r = quad * 4 + r4;
                const size_t idx = ((size_t)(b0 + r) * T_ + t) * 256 + n;
                const float x = xr[c2 * 4 + r4], m = mr[c2 * 4 + r4];
                const float z = fmaxf((c2 ? accB1[r4] : accB0[r4]) + bfv[c2], 0.f);
                const float a_ = alr[c2 * 4 + r4];
                const float ch = a_ * z + (1.f - a_) * xhs[r * 260 + n];
                const float ccv = m * x + (1.f - m) * ch;
                out[idx] = ccv;                            // imputed[:,t,:] == c_c
                ccb[r * 264 + n] = f2bf(ccv);
                pt += (fabsf(z - x) + fabsf(ch - x)) * m;
            }
        }
        lacc += pt / dent;
        __syncthreads();   // (2) ccb visible

        // ---- phase C: gates = [ccb|mtb|hd] @ Bc^T (K=1024) ----
        f32x4 acc[16] = {};
        // seg0: K 0..255 from ccb
#pragma unroll
        for (int kb = 0; kb < 2; ++kb) {
            short8 af[4];
#pragma unroll
            for (int i = 0; i < 4; ++i)
                af[i] = *(const short8*)&ccb[l16 * 264 + (kb * 4 + i) * 32 + quad * 8];
#pragma unroll
            for (int i = 0; i < 4; ++i) {
#pragma unroll
                for (int ct = 0; ct < 16; ++ct) {
                    short8 g = *(const short8*)(bC0 + ct * 16384 + (kb * 4 + i) * 32);
                    acc[ct] = __builtin_amdgcn_mfma_f32_16x16x32_bf16(af[i], g, acc[ct], 0, 0, 0);
                }
            }
        }
        // seg1: K 256..511 from mtb
#pragma unroll
        for (int kb = 0; kb < 2; ++kb) {
            short8 af[4];
#pragma unroll
            for (int i = 0; i < 4; ++i)
                af[i] = *(const short8*)&mtb[l16 * 264 + (kb * 4 + i) * 32 + quad * 8];
#pragma unroll
            for (int i = 0; i < 4; ++i) {
#pragma unroll
                for (int ct = 0; ct < 16; ++ct) {
                    short8 g = *(const short8*)(bC0 + ct * 16384 + 256 + (kb * 4 + i) * 32);
                    acc[ct] = __builtin_amdgcn_mfma_f32_16x16x32_bf16(af[i], g, acc[ct], 0, 0, 0);
                }
            }
        }
        // seg2: K 512..1023 from hd
#pragma unroll
        for (int kb = 0; kb < 4; ++kb) {
            short8 af[4];
#pragma unroll
            for (int i = 0; i < 4; ++i)
                af[i] = *(const short8*)&hd[l16 * 520 + (kb * 4 + i) * 32 + quad * 8];
#pragma unroll
            for (int i = 0; i < 4; ++i) {
#pragma unroll
                for (int ct = 0; ct < 16; ++ct) {
                    short8 g = *(const short8*)(bC0 + ct * 16384 + 512 + (kb * 4 + i) * 32);
                    acc[ct] = __builtin_amdgcn_mfma_f32_16x16x32_bf16(af[i], g, acc[ct], 0, 0, 0);
                }
            }
        }
        __syncthreads();   // (3) all hd reads done before epilogue rewrites hd

        // ---- phase C epilogue: per-wave gate exchange + LSTM ----
#pragma unroll
        for (int ct = 0; ct < 16; ++ct) {
#pragma unroll
            for (int r4 = 0; r4 < 4; ++r4)
                scr[(quad * 4 + r4) * 20 + l16] = acc[ct][r4] + bpl[ct];
            // same-wave LDS ordering: writes above complete before this read
            const float4 g4 = *(const float4*)&scr[rme * 20 + jj * 4];   // i,f,g,o
            const int j = w * 64 + ct * 4 + jj;
            const float cn = sigm(g4.y) * creg[ct] + sigm(g4.x) * tanhf(g4.z);
            const float hn = sigm(g4.w) * tanhf(cn);
            creg[ct] = cn;
            if (t < T_ - 1) {
                hd[rme * 520 + j] = f2bf(hn * bf2f(ghr[ct]));            // decayed h for t+1
            } else {
                out[6553600 + (size_t)gb * 512 + j] = hn;                // final h
            }
        }
        __syncthreads();   // (4) new hd / freed scr before next t
    }

    // ---- per-wg loss partial ----
    for (int off = 32; off; off >>= 1) lacc += __shfl_down(lacc, off);
    if (lane == 0) red[w] = lacc;
    __syncthreads();
    if (tid == 0) {
        float s = 0.f;
        for (int i = 0; i < 8; ++i) s += red[i];
        partials[blockIdx.x] = s;
    }
}

__global__ __launch_bounds__(64) void k_fin(unsigned char* __restrict__ wsb,
                                            float* __restrict__ out) {
    if (threadIdx.x == 0) {
        const float* partials = (const float*)(wsb + OB_NUM2);
        float s = 0.f;
        for (int i = 0; i < 16; ++i) s += partials[i];
        out[6684672] = s / 300.0f;
    }
}

extern "C" void kernel_launch(void* const* d_in, const int* in_sizes, int n_in,
                              void* d_out, int out_size, void* d_ws, size_t ws_size,
                              hipStream_t stream) {
    (void)in_sizes; (void)n_in; (void)out_size; (void)ws_size;
    const float* values = (const float*)d_in[0];
    const float* masks  = (const float*)d_in[1];
    const float* deltas = (const float*)d_in[2];
    const float* W_td_h = (const float*)d_in[3];
    const float* b_td_h = (const float*)d_in[4];
    const float* W_td_x = (const float*)d_in[5];
    const float* b_td_x = (const float*)d_in[6];
    const float* W_hist = (const float*)d_in[7];
    const float* b_hist = (const float*)d_in[8];
    const float* W_feat = (const float*)d_in[9];
    const float* b_feat = (const float*)d_in[10];
    const float* W_comb = (const float*)d_in[11];
    const float* b_comb = (const float*)d_in[12];
    const float* W_ih   = (const float*)d_in[13];
    const float* W_hh   = (const float*)d_in[14];
    const float* b_ih   = (const float*)d_in[15];
    const float* b_hh   = (const float*)d_in[16];

    unsigned char* wsb = (unsigned char*)d_ws;
    float* out = (float*)d_out;

    k_prep2<<<2048, 256, 0, stream>>>(W_ih, W_hh, b_ih, b_hh, W_hist, W_feat, wsb);
    k_den<<<100, 256, 0, stream>>>(masks, wsb);
    k_gamma_h<<<dim3(400, 8), 256, 0, stream>>>(deltas, W_td_h, b_td_h, wsb);
    k_alpha<<<dim3(400, 4), 256, 0, stream>>>(deltas, masks, W_td_x, b_td_x, W_comb, b_comb, wsb);
    k_rows<<<16, 512, 0, stream>>>(values, masks, b_hist, b_feat, out, wsb);
    k_fin<<<1, 64, 0, stream>>>(wsb, out);
}

// Round 2
// 4424.995 us; speedup vs baseline: 6.6277x; 6.6277x over previous
//
#include <hip/hip_runtime.h>
#include <math.h>

// RITS recurrent imputation. B=256, T=100, F=256, H=512.
// Round 4: round-2 column-parallel structure (weights LDS-resident, 256 wgs,
// 3 device barriers per t) with a CHEAP barrier: cross-wg data uses
// write-through-to-LLC stores (sc0 sc1), barrier = relaxed agent atomic +
// relaxed spin + one acquire fence (buffer_inv). No buffer_wbl2, no
// threadfence. Arithmetic identical to round 2 (absmax should match).

#define T_ 100

typedef unsigned short ushortT;
typedef __attribute__((ext_vector_type(8))) short short8;
typedef __attribute__((ext_vector_type(4))) float f32x4;

// ---- workspace byte offsets ----
#define OB_H      0u          // fp32 h [256*512] (unused, kept for init layout)
#define OB_C      524288u     // fp32 c
#define OB_HD0    1048576u    // bf16 hdec buf0 [256*512]
#define OB_HD1    1310720u    // bf16 hdec buf1
#define OB_XH     1572864u    // fp32 x_h [256*256]
#define OB_XCB    1835008u    // bf16 x_c
#define OB_CCB    1966080u    // bf16 c_c
#define OB_NUM2   2097152u    // fp32 [100*64] loss partials
#define OB_DEN    2122752u    // fp32 [128]
#define OB_CNT    2123264u    // u32 sync counter
#define OB_BIASP  2123776u    // fp32 [2048] packed b_ih+b_hh
#define OB_BA     2131968u    // bf16 W_hist [256*512]
#define OB_BB     2394112u    // bf16 Wf masked [256*256]
#define OB_BC     2525184u    // bf16 packed [2048*1024] = [wihp|whhp]
#define OB_MT     6719488u    // bf16 masks time-major [100*256*256]
#define OB_GH     19826688u   // bf16 gamma_h [25600*512]
#define OB_AL     46041088u   // bf16 alpha [25600*256]

__device__ __forceinline__ float sigm(float x) { return 1.0f / (1.0f + expf(-x)); }

__device__ __forceinline__ ushortT f2bf(float f) {
    union { float f; unsigned u; } v; v.f = f;
    unsigned r = v.u + 0x7fffu + ((v.u >> 16) & 1u);   // RNE
    return (ushortT)(r >> 16);
}
__device__ __forceinline__ float bf2f(ushortT h) {
    union { unsigned u; float f; } v; v.u = ((unsigned)h) << 16; return v.f;
}

// write-through-to-LLC stores: retire (vmcnt) at the coherence point, so a
// __syncthreads (which drains vmcnt) + relaxed atomic publishes them agent-wide
// without any buffer_wbl2.
__device__ __forceinline__ void st_bf16_wt(ushortT* p, ushortT v) {
    asm volatile("global_store_short %0, %1, off sc0 sc1" :: "v"(p), "v"((unsigned)v) : "memory");
}
__device__ __forceinline__ void st_f32_wt(float* p, float v) {
    asm volatile("global_store_dword %0, %1, off sc0 sc1" :: "v"(p), "v"(v) : "memory");
}

__device__ __forceinline__ void gsync(unsigned* cnt, unsigned epoch) {
    __syncthreads();   // compiler drains vmcnt(0) before s_barrier -> wt stores at LLC
    if (threadIdx.x == 0) {
        asm volatile("s_waitcnt vmcnt(0)" ::: "memory");
        __hip_atomic_fetch_add(cnt, 1u, __ATOMIC_RELAXED, __HIP_MEMORY_SCOPE_AGENT);
        unsigned want = epoch * 256u;
        while (__hip_atomic_load(cnt, __ATOMIC_RELAXED, __HIP_MEMORY_SCOPE_AGENT) < want)
            __builtin_amdgcn_s_sleep(2);
        __builtin_amdgcn_fence(__ATOMIC_ACQUIRE, "agent");   // buffer_inv (clean-line drop)
    }
    __syncthreads();
}

// ---------------- prep kernels (identical numerics) ----------------

__global__ __launch_bounds__(256) void k_init2(unsigned char* wsb) {
    unsigned i = blockIdx.x * 256u + threadIdx.x;   // 1280 blocks: 327,680 words
    unsigned* w = (unsigned*)wsb;
    if (i < 327680u) w[i] = 0u;                     // h, c, hdec buf0
    if (i == 0) *(unsigned*)(wsb + OB_CNT) = 0u;
}

__global__ __launch_bounds__(256) void k_prep2(const float* __restrict__ W_ih,
                                               const float* __restrict__ W_hh,
                                               const float* __restrict__ b_ih,
                                               const float* __restrict__ b_hh,
                                               const float* __restrict__ W_hist,
                                               const float* __restrict__ W_feat,
                                               unsigned char* wsb) {
    ushortT* Bc = (ushortT*)(wsb + OB_BC);
    ushortT* Ba = (ushortT*)(wsb + OB_BA);
    ushortT* Bb = (ushortT*)(wsb + OB_BB);
    float* biasp = (float*)(wsb + OB_BIASP);
    int n = blockIdx.x;                  // packed row, n = 4*j + g
    int j = n >> 2, g = n & 3;
    int src = g * 512 + j;
    for (int k = threadIdx.x; k < 512; k += 256) {
        Bc[(size_t)n * 1024 + k]       = f2bf(W_ih[(size_t)src * 512 + k]);
        Bc[(size_t)n * 1024 + 512 + k] = f2bf(W_hh[(size_t)src * 512 + k]);
        if (n < 256) {
            Ba[(size_t)n * 512 + k] = f2bf(W_hist[(size_t)n * 512 + k]);
            if (k < 256) Bb[(size_t)n * 256 + k] = (k == n) ? 0 : f2bf(W_feat[(size_t)n * 256 + k]);
        }
    }
    if (threadIdx.x == 0) biasp[n] = b_ih[src] + b_hh[src];
}

__global__ __launch_bounds__(256) void k_den(const float* __restrict__ masks, unsigned char* wsb) {
    __shared__ float red[256];
    float* den = (float*)(wsb + OB_DEN);
    int t = blockIdx.x;
    float s = 0.0f;
    for (int idx = threadIdx.x; idx < 256 * 256; idx += 256) {
        int b = idx >> 8, f = idx & 255;
        s += masks[((size_t)b * T_ + t) * 256 + f];
    }
    red[threadIdx.x] = s; __syncthreads();
    for (int st = 128; st > 0; st >>= 1) { if (threadIdx.x < st) red[threadIdx.x] += red[threadIdx.x + st]; __syncthreads(); }
    if (threadIdx.x == 0) den[t] = red[0];
}

__global__ __launch_bounds__(256) void k_maskt(const float* __restrict__ masks, unsigned char* wsb) {
    ushortT* mt = (ushortT*)(wsb + OB_MT);
    unsigned gidx = blockIdx.x * 256u + threadIdx.x;   // 6400 blocks -> 1,638,400
    int f4 = gidx & 63;
    unsigned rest = gidx >> 6;                          // 0..25599
    int t = rest % 100, b = rest / 100;
    float4 m = *(const float4*)(masks + ((size_t)b * T_ + t) * 256 + f4 * 4);
    size_t o = ((size_t)t * 256 + b) * 256 + f4 * 4;
    mt[o + 0] = f2bf(m.x); mt[o + 1] = f2bf(m.y); mt[o + 2] = f2bf(m.z); mt[o + 3] = f2bf(m.w);
}

// gamma_h: [25600,512] = exp(-relu(D @ W_td_h.T + b)), K=256 (fp32 tile GEMM)
__global__ __launch_bounds__(256) void k_gamma_h(const float* __restrict__ deltas,
                                                 const float* __restrict__ W,
                                                 const float* __restrict__ bias,
                                                 unsigned char* wsb) {
    ushortT* gh = (ushortT*)(wsb + OB_GH);
    __shared__ float As[16][65];
    __shared__ float Bs[16][65];
    int tid = threadIdx.x;
    int tx = tid & 15, ty = tid >> 4;
    int mb = blockIdx.x * 64, nb = blockIdx.y * 64;
    int lr = tid >> 2, lk = (tid & 3) * 4;
    float acc[4][4] = {};
    for (int k0 = 0; k0 < 256; k0 += 16) {
        float4 a = *(const float4*)(deltas + (size_t)(mb + lr) * 256 + k0 + lk);
        float4 b = *(const float4*)(W + (size_t)(nb + lr) * 256 + k0 + lk);
        As[lk + 0][lr] = a.x; As[lk + 1][lr] = a.y; As[lk + 2][lr] = a.z; As[lk + 3][lr] = a.w;
        Bs[lk + 0][lr] = b.x; Bs[lk + 1][lr] = b.y; Bs[lk + 2][lr] = b.z; Bs[lk + 3][lr] = b.w;
        __syncthreads();
#pragma unroll
        for (int kk = 0; kk < 16; kk++) {
            float av[4], bv[4];
#pragma unroll
            for (int i = 0; i < 4; i++) av[i] = As[kk][ty * 4 + i];
#pragma unroll
            for (int j = 0; j < 4; j++) bv[j] = Bs[kk][tx * 4 + j];
#pragma unroll
            for (int i = 0; i < 4; i++)
#pragma unroll
                for (int j = 0; j < 4; j++) acc[i][j] = fmaf(av[i], bv[j], acc[i][j]);
        }
        __syncthreads();
    }
#pragma unroll
    for (int i = 0; i < 4; i++) {
        int r = mb + ty * 4 + i;
#pragma unroll
        for (int j = 0; j < 4; j++) {
            int n = nb + tx * 4 + j;
            float v = acc[i][j] + bias[n];
            gh[(size_t)r * 512 + n] = f2bf(expf(-fmaxf(v, 0.0f)));
        }
    }
}

// alpha: [25600,256] = sigmoid([gamma_x|m] @ W_comb.T + b), K=512
__global__ __launch_bounds__(256) void k_alpha(const float* __restrict__ deltas,
                                               const float* __restrict__ masks,
                                               const float* __restrict__ Wtdx,
                                               const float* __restrict__ btdx,
                                               const float* __restrict__ Wc,
                                               const float* __restrict__ bc,
                                               unsigned char* wsb) {
    ushortT* al = (ushortT*)(wsb + OB_AL);
    __shared__ float As[16][65];
    __shared__ float Bs[16][65];
    int tid = threadIdx.x;
    int tx = tid & 15, ty = tid >> 4;
    int mb = blockIdx.x * 64, nb = blockIdx.y * 64;
    int lr = tid >> 2, lk = (tid & 3) * 4;
    float acc[4][4] = {};
    for (int k0 = 0; k0 < 512; k0 += 16) {
        int kg = k0 + lk;
        float4 a;
        if (kg < 256) {
            float4 d4 = *(const float4*)(deltas + (size_t)(mb + lr) * 256 + kg);
            a.x = expf(-fmaxf(d4.x * Wtdx[(size_t)(kg + 0) * 257] + btdx[kg + 0], 0.0f));
            a.y = expf(-fmaxf(d4.y * Wtdx[(size_t)(kg + 1) * 257] + btdx[kg + 1], 0.0f));
            a.z = expf(-fmaxf(d4.z * Wtdx[(size_t)(kg + 2) * 257] + btdx[kg + 2], 0.0f));
            a.w = expf(-fmaxf(d4.w * Wtdx[(size_t)(kg + 3) * 257] + btdx[kg + 3], 0.0f));
        } else {
            a = *(const float4*)(masks + (size_t)(mb + lr) * 256 + (kg - 256));
        }
        float4 b = *(const float4*)(Wc + (size_t)(nb + lr) * 512 + kg);
        As[lk + 0][lr] = a.x; As[lk + 1][lr] = a.y; As[lk + 2][lr] = a.z; As[lk + 3][lr] = a.w;
        Bs[lk + 0][lr] = b.x; Bs[lk + 1][lr] = b.y; Bs[lk + 2][lr] = b.z; Bs[lk + 3][lr] = b.w;
        __syncthreads();
#pragma unroll
        for (int kk = 0; kk < 16; kk++) {
            float av[4], bv[4];
#pragma unroll
            for (int i = 0; i < 4; i++) av[i] = As[kk][ty * 4 + i];
#pragma unroll
            for (int j = 0; j < 4; j++) bv[j] = Bs[kk][tx * 4 + j];
#pragma unroll
            for (int i = 0; i < 4; i++)
#pragma unroll
                for (int j = 0; j < 4; j++) acc[i][j] = fmaf(av[i], bv[j], acc[i][j]);
        }
        __syncthreads();
    }
#pragma unroll
    for (int i = 0; i < 4; i++) {
        int r = mb + ty * 4 + i;
#pragma unroll
        for (int j = 0; j < 4; j++) {
            int n = nb + tx * 4 + j;
            al[(size_t)r * 256 + n] = f2bf(sigm(acc[i][j] + bc[n]));
        }
    }
}

// ---------------- persistent kernel ----------------

__global__ __launch_bounds__(256, 1) void k_persist(const float* __restrict__ values,
                                                    const float* __restrict__ masks,
                                                    const float* __restrict__ b_hist,
                                                    const float* __restrict__ b_feat,
                                                    float* __restrict__ out,
                                                    unsigned char* __restrict__ wsb) {
    float* c_buf = (float*)(wsb + OB_C);
    ushortT* hd[2] = { (ushortT*)(wsb + OB_HD0), (ushortT*)(wsb + OB_HD1) };
    float* xh = (float*)(wsb + OB_XH);
    ushortT* xcb = (ushortT*)(wsb + OB_XCB);
    ushortT* ccb = (ushortT*)(wsb + OB_CCB);
    float* num2 = (float*)(wsb + OB_NUM2);
    const float* den = (const float*)(wsb + OB_DEN);
    unsigned* cnt = (unsigned*)(wsb + OB_CNT);
    const float* biasp = (const float*)(wsb + OB_BIASP);
    const ushortT* Ba = (const ushortT*)(wsb + OB_BA);
    const ushortT* Bb = (const ushortT*)(wsb + OB_BB);
    const ushortT* Bc = (const ushortT*)(wsb + OB_BC);
    const ushortT* mt = (const ushortT*)(wsb + OB_MT);
    const ushortT* gh = (const ushortT*)(wsb + OB_GH);
    const ushortT* al = (const ushortT*)(wsb + OB_AL);

    __shared__ ushortT ldsBc[16 * 1032];   // 33024 B, +8 pad breaks bank conflicts
    __shared__ ushortT ldsBa[16 * 520];    // 16640 B
    __shared__ ushortT ldsBb[16 * 264];    //  8448 B
    __shared__ float scr[4 * 256];         //  4096 B
    __shared__ float lossSlots[8];

    const int wg = blockIdx.x, tid = threadIdx.x;
    const int wave = tid >> 6, lane = tid & 63, quad = lane >> 4, l16 = lane & 15;

    // ---- load LDS weight slices (once) ----
    {
        int n0 = (wg & 127) * 16;
        for (int i = tid; i < 2048; i += 256) {       // 16 rows x 128 chunks of 8
            int r = i >> 7, c = i & 127;
            *(short8*)&ldsBc[r * 1032 + c * 8] = *(const short8*)&Bc[(size_t)(n0 + r) * 1024 + c * 8];
        }
        if (wg < 64) {
            int nA = (wg & 15) * 16;
            for (int i = tid; i < 1024; i += 256) {   // 16 x 64
                int r = i >> 6, c = i & 63;
                *(short8*)&ldsBa[r * 520 + c * 8] = *(const short8*)&Ba[(size_t)(nA + r) * 512 + c * 8];
            }
            for (int i = tid; i < 512; i += 256) {    // 16 x 32
                int r = i >> 5, c = i & 31;
                *(short8*)&ldsBb[r * 264 + c * 8] = *(const short8*)&Bb[(size_t)(nA + r) * 256 + c * 8];
            }
        }
        __syncthreads();
    }

    unsigned epoch = 0;
#pragma unroll 1
    for (int t = 0; t < T_; ++t) {
        const ushortT* hdA = hd[t & 1];
        ushortT* hdW = hd[(t + 1) & 1];

        // ---- phase A: x_h = hdec @ W_hist.T ----
        if (wg < 64) {
            int mb = (wg >> 4) * 64, nb = (wg & 15) * 16;
            int rowA = mb + wave * 16;
            f32x4 acc = {0.f, 0.f, 0.f, 0.f};
            const ushortT* aBase = hdA + (size_t)(rowA + l16) * 512 + quad * 8;
#pragma unroll 4
            for (int kc = 0; kc < 16; ++kc) {
                short8 a = *(const short8*)(aBase + kc * 32);
                short8 b = *(const short8*)&ldsBa[l16 * 520 + kc * 32 + quad * 8];
                acc = __builtin_amdgcn_mfma_f32_16x16x32_bf16(a, b, acc, 0, 0, 0);
            }
            int n = nb + l16;
            float bh = b_hist[n];
            float ls = 0.f;
#pragma unroll
            for (int r4 = 0; r4 < 4; ++r4) {
                int r = rowA + quad * 4 + r4;
                float v = acc[r4] + bh;
                size_t idx = ((size_t)r * T_ + t) * 256 + n;
                float x = values[idx], m = masks[idx];
                st_f32_wt(&xh[r * 256 + n], v);
                st_bf16_wt(&xcb[r * 256 + n], f2bf(m * x + (1.f - m) * v));
                ls += fabsf(v - x) * m;
            }
            for (int off = 32; off; off >>= 1) ls += __shfl_down(ls, off);
            if (lane == 0) lossSlots[wave] = ls;
        }
        gsync(cnt, ++epoch);

        // ---- phase B: z_h = x_c @ Wf.T; c_h, c_c, losses ----
        if (wg < 64) {
            int mb = (wg >> 4) * 64, nb = (wg & 15) * 16;
            int rowA = mb + wave * 16;
            f32x4 acc = {0.f, 0.f, 0.f, 0.f};
            const ushortT* aBase = xcb + (size_t)(rowA + l16) * 256 + quad * 8;
#pragma unroll 4
            for (int kc = 0; kc < 8; ++kc) {
                short8 a = *(const short8*)(aBase + kc * 32);
                short8 b = *(const short8*)&ldsBb[l16 * 264 + kc * 32 + quad * 8];
                acc = __builtin_amdgcn_mfma_f32_16x16x32_bf16(a, b, acc, 0, 0, 0);
            }
            int n = nb + l16;
            float bfv = b_feat[n];
            float ls = 0.f;
#pragma unroll
            for (int r4 = 0; r4 < 4; ++r4) {
                int r = rowA + quad * 4 + r4;
                float z = fmaxf(acc[r4] + bfv, 0.f);
                size_t idx = ((size_t)r * T_ + t) * 256 + n;
                float a_ = bf2f(al[idx]);
                float xhv = xh[r * 256 + n];
                float ch = a_ * z + (1.f - a_) * xhv;
                float x = values[idx], m = masks[idx];
                float ccv = m * x + (1.f - m) * ch;
                out[idx] = ccv;                       // imputed[:,t,:] == c_c
                st_bf16_wt(&ccb[r * 256 + n], f2bf(ccv));
                ls += (fabsf(z - x) + fabsf(ch - x)) * m;
            }
            for (int off = 32; off; off >>= 1) ls += __shfl_down(ls, off);
            if (lane == 0) lossSlots[4 + wave] = ls;
            __syncthreads();
            if (tid == 0) {
                float s = 0.f;
                for (int i = 0; i < 8; ++i) s += lossSlots[i];
                st_f32_wt(&num2[t * 64 + wg], s);
            }
        }
        gsync(cnt, ++epoch);

        // ---- phase C: gates = [cc|m|hdec] @ BcT (K=1024) + LSTM ----
        {
            int mb = (wg >> 7) * 128, nb = (wg & 127) * 16;
            int r0 = mb + wave * 32;
            f32x4 acc0 = {0.f, 0.f, 0.f, 0.f}, acc1 = {0.f, 0.f, 0.f, 0.f};
            const ushortT* mtT = mt + (size_t)t * 65536;
            {
                const ushortT* a0p = ccb + (size_t)(r0 + l16) * 256 + quad * 8;
                const ushortT* a1p = a0p + 16 * 256;
#pragma unroll 4
                for (int kc = 0; kc < 8; ++kc) {
                    short8 a0 = *(const short8*)(a0p + kc * 32);
                    short8 a1 = *(const short8*)(a1p + kc * 32);
                    short8 b = *(const short8*)&ldsBc[l16 * 1032 + kc * 32 + quad * 8];
                    acc0 = __builtin_amdgcn_mfma_f32_16x16x32_bf16(a0, b, acc0, 0, 0, 0);
                    acc1 = __builtin_amdgcn_mfma_f32_16x16x32_bf16(a1, b, acc1, 0, 0, 0);
                }
            }
            {
                const ushortT* a0p = mtT + (size_t)(r0 + l16) * 256 + quad * 8;
                const ushortT* a1p = a0p + 16 * 256;
#pragma unroll 4
                for (int kc = 0; kc < 8; ++kc) {
                    short8 a0 = *(const short8*)(a0p + kc * 32);
                    short8 a1 = *(const short8*)(a1p + kc * 32);
                    short8 b = *(const short8*)&ldsBc[l16 * 1032 + 256 + kc * 32 + quad * 8];
                    acc0 = __builtin_amdgcn_mfma_f32_16x16x32_bf16(a0, b, acc0, 0, 0, 0);
                    acc1 = __builtin_amdgcn_mfma_f32_16x16x32_bf16(a1, b, acc1, 0, 0, 0);
                }
            }
            {
                const ushortT* a0p = hdA + (size_t)(r0 + l16) * 512 + quad * 8;
                const ushortT* a1p = a0p + 16 * 512;
#pragma unroll 4
                for (int kc = 0; kc < 16; ++kc) {
                    short8 a0 = *(const short8*)(a0p + kc * 32);
                    short8 a1 = *(const short8*)(a1p + kc * 32);
                    short8 b = *(const short8*)&ldsBc[l16 * 1032 + 512 + kc * 32 + quad * 8];
                    acc0 = __builtin_amdgcn_mfma_f32_16x16x32_bf16(a0, b, acc0, 0, 0, 0);
                    acc1 = __builtin_amdgcn_mfma_f32_16x16x32_bf16(a1, b, acc1, 0, 0, 0);
                }
            }
            float bp = biasp[nb + l16];
            float* ms = scr + wave * 256;
#pragma unroll
            for (int tt = 0; tt < 2; ++tt) {
                __syncthreads();                       // scr reuse fence
                int Mb = r0 + tt * 16;
#pragma unroll
                for (int r4 = 0; r4 < 4; ++r4) {
                    float g = (tt ? acc1[r4] : acc0[r4]) + bp;
                    ms[(quad * 4 + r4) * 16 + l16] = g;
                }
                __syncthreads();                       // writes visible
                int rloc = lane >> 2, u = lane & 3;
                float gi = ms[rloc * 16 + u * 4 + 0];
                float gf = ms[rloc * 16 + u * 4 + 1];
                float gg = ms[rloc * 16 + u * 4 + 2];
                float go = ms[rloc * 16 + u * 4 + 3];
                int b = Mb + rloc;
                int j = (nb >> 2) + u;
                float cold = c_buf[(size_t)b * 512 + j];
                float cn = sigm(gf) * cold + sigm(gi) * tanhf(gg);
                float hn = sigm(go) * tanhf(cn);
                st_f32_wt(&c_buf[(size_t)b * 512 + j], cn);
                if (t < T_ - 1) {
                    float gv = bf2f(gh[((size_t)b * T_ + t + 1) * 512 + j]);
                    st_bf16_wt(&hdW[(size_t)b * 512 + j], f2bf(hn * gv));
                } else {
                    out[6553600 + (size_t)b * 512 + j] = hn;   // final h (kernel-end flush)
                }
            }
        }
        gsync(cnt, ++epoch);
    }

    // ---- finalize ----
    if (wg == 0) {
        float v = 0.f;
        if (tid < T_) {
            float s = 0.f;
            for (int w = 0; w < 64; ++w) s += num2[tid * 64 + w];
            v = s / (den[tid] + 1e-9f);
        }
        scr[tid] = v;
        __syncthreads();
        for (int s = 128; s > 0; s >>= 1) { if (tid < s) scr[tid] += scr[tid + s]; __syncthreads(); }
        if (tid == 0) out[6684672] = scr[0] / 300.0f;
    }
}

extern "C" void kernel_launch(void* const* d_in, const int* in_sizes, int n_in,
                              void* d_out, int out_size, void* d_ws, size_t ws_size,
                              hipStream_t stream) {
    (void)in_sizes; (void)n_in; (void)out_size; (void)ws_size;
    const float* values = (const float*)d_in[0];
    const float* masks  = (const float*)d_in[1];
    const float* deltas = (const float*)d_in[2];
    const float* W_td_h = (const float*)d_in[3];
    const float* b_td_h = (const float*)d_in[4];
    const float* W_td_x = (const float*)d_in[5];
    const float* b_td_x = (const float*)d_in[6];
    const float* W_hist = (const float*)d_in[7];
    const float* b_hist = (const float*)d_in[8];
    const float* W_feat = (const float*)d_in[9];
    const float* b_feat = (const float*)d_in[10];
    const float* W_comb = (const float*)d_in[11];
    const float* b_comb = (const float*)d_in[12];
    const float* W_ih   = (const float*)d_in[13];
    const float* W_hh   = (const float*)d_in[14];
    const float* b_ih   = (const float*)d_in[15];
    const float* b_hh   = (const float*)d_in[16];

    unsigned char* wsb = (unsigned char*)d_ws;
    float* out = (float*)d_out;

    k_init2<<<1280, 256, 0, stream>>>(wsb);
    k_prep2<<<2048, 256, 0, stream>>>(W_ih, W_hh, b_ih, b_hh, W_hist, W_feat, wsb);
    k_den<<<100, 256, 0, stream>>>(masks, wsb);
    k_maskt<<<6400, 256, 0, stream>>>(masks, wsb);
    k_gamma_h<<<dim3(400, 8), 256, 0, stream>>>(deltas, W_td_h, b_td_h, wsb);
    k_alpha<<<dim3(400, 4), 256, 0, stream>>>(deltas, masks, W_td_x, b_td_x, W_comb, b_comb, wsb);
    k_persist<<<256, 256, 0, stream>>>(values, masks, b_hist, b_feat, out, wsb);
}

// Round 3
// 4230.948 us; speedup vs baseline: 6.9317x; 1.0459x over previous
//
#include <hip/hip_runtime.h>
#include <math.h>

// RITS recurrent imputation. B=256, T=100, F=256, H=512.
// Round 5: column-parallel persistent kernel, barriers WITHOUT any cache
// fence. Cross-wg buffers (xcb, ccb, hd, num2) are written with
// write-through-to-LLC stores (sc0 sc1) and read with agent-scope relaxed
// atomic loads (sc1, bypass stale L1/L2). Read-only inputs use normal cached
// loads and stay warm in L2 across all 100 timesteps (no buffer_inv).
// x_h and the LSTM c state move to registers (wg/thread-private mappings).
// Barrier 1 (A->B) only involves the 64 A/B workgroups.
// Arithmetic order identical to round 4 (absmax must match: 0.0078125).

#define T_ 100

typedef unsigned short ushortT;
typedef __attribute__((ext_vector_type(8))) short short8;
typedef __attribute__((ext_vector_type(4))) float f32x4;

// ---- workspace byte offsets ----
#define OB_HD0    1048576u    // bf16 hdec buf0 [256*512]
#define OB_HD1    1310720u    // bf16 hdec buf1
#define OB_XCB    1835008u    // bf16 x_c
#define OB_CCB    1966080u    // bf16 c_c
#define OB_NUM2   2097152u    // fp32 [100*64] loss partials
#define OB_DEN    2122752u    // fp32 [128]
#define OB_CNT    2123264u    // u32 full-barrier counter; +128: 64-wg counter
#define OB_BIASP  2123776u    // fp32 [2048] packed b_ih+b_hh
#define OB_BA     2131968u    // bf16 W_hist [256*512]
#define OB_BB     2394112u    // bf16 Wf masked [256*256]
#define OB_BC     2525184u    // bf16 packed [2048*1024] = [wihp|whhp]
#define OB_MT     6719488u    // bf16 masks time-major [100*256*256]
#define OB_GH     19826688u   // bf16 gamma_h [25600*512]
#define OB_AL     46041088u   // bf16 alpha [25600*256]

__device__ __forceinline__ float sigm(float x) { return 1.0f / (1.0f + expf(-x)); }

__device__ __forceinline__ ushortT f2bf(float f) {
    union { float f; unsigned u; } v; v.f = f;
    unsigned r = v.u + 0x7fffu + ((v.u >> 16) & 1u);   // RNE
    return (ushortT)(r >> 16);
}
__device__ __forceinline__ float bf2f(ushortT h) {
    union { unsigned u; float f; } v; v.u = ((unsigned)h) << 16; return v.f;
}

// write-through-to-LLC stores: once vmcnt retires they are at the coherence
// point; a drained barrier + relaxed agent atomic publishes them chip-wide.
__device__ __forceinline__ void st_bf16_wt(ushortT* p, ushortT v) {
    asm volatile("global_store_short %0, %1, off sc0 sc1" :: "v"(p), "v"((unsigned)v) : "memory");
}
__device__ __forceinline__ void st_f32_wt(float* p, float v) {
    asm volatile("global_store_dword %0, %1, off sc0 sc1" :: "v"(p), "v"(v) : "memory");
}

// coherent reads: agent-scope relaxed atomic loads (emit global_load ... sc1,
// bypassing potentially-stale L1/L2). Compiler tracks the dependency, so no
// manual waitcnt is needed and loads pipeline freely.
__device__ __forceinline__ short8 ldc16(const ushortT* p) {
    union { struct { unsigned long long a, b; } q; short8 s; } u;
    u.q.a = __hip_atomic_load((const unsigned long long*)p,     __ATOMIC_RELAXED, __HIP_MEMORY_SCOPE_AGENT);
    u.q.b = __hip_atomic_load((const unsigned long long*)p + 1, __ATOMIC_RELAXED, __HIP_MEMORY_SCOPE_AGENT);
    return u.s;
}
__device__ __forceinline__ float ldcf(const float* p) {
    union { unsigned u; float f; } w;
    w.u = __hip_atomic_load((const unsigned*)p, __ATOMIC_RELAXED, __HIP_MEMORY_SCOPE_AGENT);
    return w.f;
}

// barrier: all threads drain their wt stores, then rank-0 bumps the counter
// and spins. No acquire fence — readers use coherent loads instead.
__device__ __forceinline__ void gbar(unsigned* cnt, unsigned want) {
    asm volatile("s_waitcnt vmcnt(0)" ::: "memory");   // wt stores at LLC (all waves)
    __syncthreads();
    if (threadIdx.x == 0) {
        __hip_atomic_fetch_add(cnt, 1u, __ATOMIC_RELAXED, __HIP_MEMORY_SCOPE_AGENT);
        while (__hip_atomic_load(cnt, __ATOMIC_RELAXED, __HIP_MEMORY_SCOPE_AGENT) < want)
            __builtin_amdgcn_s_sleep(2);
    }
    __syncthreads();
}

// ---------------- prep kernels (identical numerics) ----------------

__global__ __launch_bounds__(256) void k_init2(unsigned char* wsb) {
    unsigned i = blockIdx.x * 256u + threadIdx.x;
    unsigned* w = (unsigned*)wsb;
    if (i < 327680u) w[i] = 0u;                     // covers hdec buf0 (+ legacy range)
    if (i == 0) {
        *(unsigned*)(wsb + OB_CNT) = 0u;
        *(unsigned*)(wsb + OB_CNT + 128) = 0u;
    }
}

__global__ __launch_bounds__(256) void k_prep2(const float* __restrict__ W_ih,
                                               const float* __restrict__ W_hh,
                                               const float* __restrict__ b_ih,
                                               const float* __restrict__ b_hh,
                                               const float* __restrict__ W_hist,
                                               const float* __restrict__ W_feat,
                                               unsigned char* wsb) {
    ushortT* Bc = (ushortT*)(wsb + OB_BC);
    ushortT* Ba = (ushortT*)(wsb + OB_BA);
    ushortT* Bb = (ushortT*)(wsb + OB_BB);
    float* biasp = (float*)(wsb + OB_BIASP);
    int n = blockIdx.x;                  // packed row, n = 4*j + g
    int j = n >> 2, g = n & 3;
    int src = g * 512 + j;
    for (int k = threadIdx.x; k < 512; k += 256) {
        Bc[(size_t)n * 1024 + k]       = f2bf(W_ih[(size_t)src * 512 + k]);
        Bc[(size_t)n * 1024 + 512 + k] = f2bf(W_hh[(size_t)src * 512 + k]);
        if (n < 256) {
            Ba[(size_t)n * 512 + k] = f2bf(W_hist[(size_t)n * 512 + k]);
            if (k < 256) Bb[(size_t)n * 256 + k] = (k == n) ? 0 : f2bf(W_feat[(size_t)n * 256 + k]);
        }
    }
    if (threadIdx.x == 0) biasp[n] = b_ih[src] + b_hh[src];
}

__global__ __launch_bounds__(256) void k_den(const float* __restrict__ masks, unsigned char* wsb) {
    __shared__ float red[256];
    float* den = (float*)(wsb + OB_DEN);
    int t = blockIdx.x;
    float s = 0.0f;
    for (int idx = threadIdx.x; idx < 256 * 256; idx += 256) {
        int b = idx >> 8, f = idx & 255;
        s += masks[((size_t)b * T_ + t) * 256 + f];
    }
    red[threadIdx.x] = s; __syncthreads();
    for (int st = 128; st > 0; st >>= 1) { if (threadIdx.x < st) red[threadIdx.x] += red[threadIdx.x + st]; __syncthreads(); }
    if (threadIdx.x == 0) den[t] = red[0];
}

__global__ __launch_bounds__(256) void k_maskt(const float* __restrict__ masks, unsigned char* wsb) {
    ushortT* mt = (ushortT*)(wsb + OB_MT);
    unsigned gidx = blockIdx.x * 256u + threadIdx.x;   // 6400 blocks -> 1,638,400
    int f4 = gidx & 63;
    unsigned rest = gidx >> 6;                          // 0..25599
    int t = rest % 100, b = rest / 100;
    float4 m = *(const float4*)(masks + ((size_t)b * T_ + t) * 256 + f4 * 4);
    size_t o = ((size_t)t * 256 + b) * 256 + f4 * 4;
    mt[o + 0] = f2bf(m.x); mt[o + 1] = f2bf(m.y); mt[o + 2] = f2bf(m.z); mt[o + 3] = f2bf(m.w);
}

// gamma_h: [25600,512] = exp(-relu(D @ W_td_h.T + b)), K=256 (fp32 tile GEMM)
__global__ __launch_bounds__(256) void k_gamma_h(const float* __restrict__ deltas,
                                                 const float* __restrict__ W,
                                                 const float* __restrict__ bias,
                                                 unsigned char* wsb) {
    ushortT* gh = (ushortT*)(wsb + OB_GH);
    __shared__ float As[16][65];
    __shared__ float Bs[16][65];
    int tid = threadIdx.x;
    int tx = tid & 15, ty = tid >> 4;
    int mb = blockIdx.x * 64, nb = blockIdx.y * 64;
    int lr = tid >> 2, lk = (tid & 3) * 4;
    float acc[4][4] = {};
    for (int k0 = 0; k0 < 256; k0 += 16) {
        float4 a = *(const float4*)(deltas + (size_t)(mb + lr) * 256 + k0 + lk);
        float4 b = *(const float4*)(W + (size_t)(nb + lr) * 256 + k0 + lk);
        As[lk + 0][lr] = a.x; As[lk + 1][lr] = a.y; As[lk + 2][lr] = a.z; As[lk + 3][lr] = a.w;
        Bs[lk + 0][lr] = b.x; Bs[lk + 1][lr] = b.y; Bs[lk + 2][lr] = b.z; Bs[lk + 3][lr] = b.w;
        __syncthreads();
#pragma unroll
        for (int kk = 0; kk < 16; kk++) {
            float av[4], bv[4];
#pragma unroll
            for (int i = 0; i < 4; i++) av[i] = As[kk][ty * 4 + i];
#pragma unroll
            for (int j = 0; j < 4; j++) bv[j] = Bs[kk][tx * 4 + j];
#pragma unroll
            for (int i = 0; i < 4; i++)
#pragma unroll
                for (int j = 0; j < 4; j++) acc[i][j] = fmaf(av[i], bv[j], acc[i][j]);
        }
        __syncthreads();
    }
#pragma unroll
    for (int i = 0; i < 4; i++) {
        int r = mb + ty * 4 + i;
#pragma unroll
        for (int j = 0; j < 4; j++) {
            int n = nb + tx * 4 + j;
            float v = acc[i][j] + bias[n];
            gh[(size_t)r * 512 + n] = f2bf(expf(-fmaxf(v, 0.0f)));
        }
    }
}

// alpha: [25600,256] = sigmoid([gamma_x|m] @ W_comb.T + b), K=512
__global__ __launch_bounds__(256) void k_alpha(const float* __restrict__ deltas,
                                               const float* __restrict__ masks,
                                               const float* __restrict__ Wtdx,
                                               const float* __restrict__ btdx,
                                               const float* __restrict__ Wc,
                                               const float* __restrict__ bc,
                                               unsigned char* wsb) {
    ushortT* al = (ushortT*)(wsb + OB_AL);
    __shared__ float As[16][65];
    __shared__ float Bs[16][65];
    int tid = threadIdx.x;
    int tx = tid & 15, ty = tid >> 4;
    int mb = blockIdx.x * 64, nb = blockIdx.y * 64;
    int lr = tid >> 2, lk = (tid & 3) * 4;
    float acc[4][4] = {};
    for (int k0 = 0; k0 < 512; k0 += 16) {
        int kg = k0 + lk;
        float4 a;
        if (kg < 256) {
            float4 d4 = *(const float4*)(deltas + (size_t)(mb + lr) * 256 + kg);
            a.x = expf(-fmaxf(d4.x * Wtdx[(size_t)(kg + 0) * 257] + btdx[kg + 0], 0.0f));
            a.y = expf(-fmaxf(d4.y * Wtdx[(size_t)(kg + 1) * 257] + btdx[kg + 1], 0.0f));
            a.z = expf(-fmaxf(d4.z * Wtdx[(size_t)(kg + 2) * 257] + btdx[kg + 2], 0.0f));
            a.w = expf(-fmaxf(d4.w * Wtdx[(size_t)(kg + 3) * 257] + btdx[kg + 3], 0.0f));
        } else {
            a = *(const float4*)(masks + (size_t)(mb + lr) * 256 + (kg - 256));
        }
        float4 b = *(const float4*)(Wc + (size_t)(nb + lr) * 512 + kg);
        As[lk + 0][lr] = a.x; As[lk + 1][lr] = a.y; As[lk + 2][lr] = a.z; As[lk + 3][lr] = a.w;
        Bs[lk + 0][lr] = b.x; Bs[lk + 1][lr] = b.y; Bs[lk + 2][lr] = b.z; Bs[lk + 3][lr] = b.w;
        __syncthreads();
#pragma unroll
        for (int kk = 0; kk < 16; kk++) {
            float av[4], bv[4];
#pragma unroll
            for (int i = 0; i < 4; i++) av[i] = As[kk][ty * 4 + i];
#pragma unroll
            for (int j = 0; j < 4; j++) bv[j] = Bs[kk][tx * 4 + j];
#pragma unroll
            for (int i = 0; i < 4; i++)
#pragma unroll
                for (int j = 0; j < 4; j++) acc[i][j] = fmaf(av[i], bv[j], acc[i][j]);
        }
        __syncthreads();
    }
#pragma unroll
    for (int i = 0; i < 4; i++) {
        int r = mb + ty * 4 + i;
#pragma unroll
        for (int j = 0; j < 4; j++) {
            int n = nb + tx * 4 + j;
            al[(size_t)r * 256 + n] = f2bf(sigm(acc[i][j] + bc[n]));
        }
    }
}

// ---------------- persistent kernel ----------------

__global__ __launch_bounds__(256, 1) void k_persist(const float* __restrict__ values,
                                                    const float* __restrict__ masks,
                                                    const float* __restrict__ b_hist,
                                                    const float* __restrict__ b_feat,
                                                    float* __restrict__ out,
                                                    unsigned char* __restrict__ wsb) {
    ushortT* hd[2] = { (ushortT*)(wsb + OB_HD0), (ushortT*)(wsb + OB_HD1) };
    ushortT* xcb = (ushortT*)(wsb + OB_XCB);
    ushortT* ccb = (ushortT*)(wsb + OB_CCB);
    float* num2 = (float*)(wsb + OB_NUM2);
    const float* den = (const float*)(wsb + OB_DEN);
    unsigned* cnt2 = (unsigned*)(wsb + OB_CNT);          // full barriers
    unsigned* cnt1 = (unsigned*)(wsb + OB_CNT + 128);    // 64-wg barrier (A->B)
    const float* biasp = (const float*)(wsb + OB_BIASP);
    const ushortT* Ba = (const ushortT*)(wsb + OB_BA);
    const ushortT* Bb = (const ushortT*)(wsb + OB_BB);
    const ushortT* Bc = (const ushortT*)(wsb + OB_BC);
    const ushortT* mt = (const ushortT*)(wsb + OB_MT);
    const ushortT* gh = (const ushortT*)(wsb + OB_GH);
    const ushortT* al = (const ushortT*)(wsb + OB_AL);

    __shared__ ushortT ldsBc[16 * 1032];   // 33024 B, +8 pad breaks bank conflicts
    __shared__ ushortT ldsBa[16 * 520];    // 16640 B
    __shared__ ushortT ldsBb[16 * 264];    //  8448 B
    __shared__ float scr[4 * 256];         //  4096 B
    __shared__ float lossSlots[8];

    const int wg = blockIdx.x, tid = threadIdx.x;
    const int wave = tid >> 6, lane = tid & 63, quad = lane >> 4, l16 = lane & 15;

    // ---- load LDS weight slices (once) ----
    {
        int n0 = (wg & 127) * 16;
        for (int i = tid; i < 2048; i += 256) {       // 16 rows x 128 chunks of 8
            int r = i >> 7, c = i & 127;
            *(short8*)&ldsBc[r * 1032 + c * 8] = *(const short8*)&Bc[(size_t)(n0 + r) * 1024 + c * 8];
        }
        if (wg < 64) {
            int nA = (wg & 15) * 16;
            for (int i = tid; i < 1024; i += 256) {   // 16 x 64
                int r = i >> 6, c = i & 63;
                *(short8*)&ldsBa[r * 520 + c * 8] = *(const short8*)&Ba[(size_t)(nA + r) * 512 + c * 8];
            }
            for (int i = tid; i < 512; i += 256) {    // 16 x 32
                int r = i >> 5, c = i & 31;
                *(short8*)&ldsBb[r * 264 + c * 8] = *(const short8*)&Bb[(size_t)(nA + r) * 256 + c * 8];
            }
        }
        __syncthreads();
    }

    float creg0 = 0.f, creg1 = 0.f;        // LSTM c state (thread-private mapping)

#pragma unroll 1
    for (int t = 0; t < T_; ++t) {
        const ushortT* hdA = hd[t & 1];
        ushortT* hdW = hd[(t + 1) & 1];

        if (wg < 64) {
            int mb = (wg >> 4) * 64, nb = (wg & 15) * 16;
            int rowA = mb + wave * 16;
            int n = nb + l16;
            float xhv[4];                  // x_h stays in registers across A->B

            // ---- phase A: x_h = hdec @ W_hist.T ----
            {
                f32x4 acc = {0.f, 0.f, 0.f, 0.f};
                const ushortT* aBase = hdA + (size_t)(rowA + l16) * 512 + quad * 8;
#pragma unroll 4
                for (int kc = 0; kc < 16; ++kc) {
                    short8 a = ldc16(aBase + kc * 32);
                    short8 b = *(const short8*)&ldsBa[l16 * 520 + kc * 32 + quad * 8];
                    acc = __builtin_amdgcn_mfma_f32_16x16x32_bf16(a, b, acc, 0, 0, 0);
                }
                float bh = b_hist[n];
                float ls = 0.f;
#pragma unroll
                for (int r4 = 0; r4 < 4; ++r4) {
                    int r = rowA + quad * 4 + r4;
                    float v = acc[r4] + bh;
                    xhv[r4] = v;
                    size_t idx = ((size_t)r * T_ + t) * 256 + n;
                    float x = values[idx], m = masks[idx];
                    st_bf16_wt(&xcb[r * 256 + n], f2bf(m * x + (1.f - m) * v));
                    ls += fabsf(v - x) * m;
                }
                for (int off = 32; off; off >>= 1) ls += __shfl_down(ls, off);
                if (lane == 0) lossSlots[wave] = ls;
            }
            gbar(cnt1, (unsigned)(t + 1) * 64u);

            // ---- phase B: z_h = x_c @ Wf.T; c_h, c_c, losses ----
            {
                f32x4 acc = {0.f, 0.f, 0.f, 0.f};
                const ushortT* aBase = xcb + (size_t)(rowA + l16) * 256 + quad * 8;
#pragma unroll 4
                for (int kc = 0; kc < 8; ++kc) {
                    short8 a = ldc16(aBase + kc * 32);
                    short8 b = *(const short8*)&ldsBb[l16 * 264 + kc * 32 + quad * 8];
                    acc = __builtin_amdgcn_mfma_f32_16x16x32_bf16(a, b, acc, 0, 0, 0);
                }
                float bfv = b_feat[n];
                float ls = 0.f;
#pragma unroll
                for (int r4 = 0; r4 < 4; ++r4) {
                    int r = rowA + quad * 4 + r4;
                    float z = fmaxf(acc[r4] + bfv, 0.f);
                    size_t idx = ((size_t)r * T_ + t) * 256 + n;
                    float a_ = bf2f(al[idx]);
                    float ch = a_ * z + (1.f - a_) * xhv[r4];
                    float x = values[idx], m = masks[idx];
                    float ccv = m * x + (1.f - m) * ch;
                    out[idx] = ccv;                       // imputed[:,t,:] == c_c
                    st_bf16_wt(&ccb[r * 256 + n], f2bf(ccv));
                    ls += (fabsf(z - x) + fabsf(ch - x)) * m;
                }
                for (int off = 32; off; off >>= 1) ls += __shfl_down(ls, off);
                if (lane == 0) lossSlots[4 + wave] = ls;
                __syncthreads();
                if (tid == 0) {
                    float s = 0.f;
                    for (int i = 0; i < 8; ++i) s += lossSlots[i];
                    st_f32_wt(&num2[t * 64 + wg], s);
                }
            }
        }
        gbar(cnt2, (unsigned)(2 * t + 1) * 256u);

        // ---- phase C: gates = [cc|m|hdec] @ BcT (K=1024) + LSTM ----
        {
            int mb = (wg >> 7) * 128, nb = (wg & 127) * 16;
            int r0 = mb + wave * 32;
            f32x4 acc0 = {0.f, 0.f, 0.f, 0.f}, acc1 = {0.f, 0.f, 0.f, 0.f};
            const ushortT* mtT = mt + (size_t)t * 65536;
            {
                const ushortT* a0p = ccb + (size_t)(r0 + l16) * 256 + quad * 8;
                const ushortT* a1p = a0p + 16 * 256;
#pragma unroll 4
                for (int kc = 0; kc < 8; ++kc) {
                    short8 a0 = ldc16(a0p + kc * 32);
                    short8 a1 = ldc16(a1p + kc * 32);
                    short8 b = *(const short8*)&ldsBc[l16 * 1032 + kc * 32 + quad * 8];
                    acc0 = __builtin_amdgcn_mfma_f32_16x16x32_bf16(a0, b, acc0, 0, 0, 0);
                    acc1 = __builtin_amdgcn_mfma_f32_16x16x32_bf16(a1, b, acc1, 0, 0, 0);
                }
            }
            {
                const ushortT* a0p = mtT + (size_t)(r0 + l16) * 256 + quad * 8;
                const ushortT* a1p = a0p + 16 * 256;
#pragma unroll 4
                for (int kc = 0; kc < 8; ++kc) {
                    short8 a0 = *(const short8*)(a0p + kc * 32);    // read-only, L2-warm
                    short8 a1 = *(const short8*)(a1p + kc * 32);
                    short8 b = *(const short8*)&ldsBc[l16 * 1032 + 256 + kc * 32 + quad * 8];
                    acc0 = __builtin_amdgcn_mfma_f32_16x16x32_bf16(a0, b, acc0, 0, 0, 0);
                    acc1 = __builtin_amdgcn_mfma_f32_16x16x32_bf16(a1, b, acc1, 0, 0, 0);
                }
            }
            {
                const ushortT* a0p = hdA + (size_t)(r0 + l16) * 512 + quad * 8;
                const ushortT* a1p = a0p + 16 * 512;
#pragma unroll 4
                for (int kc = 0; kc < 16; ++kc) {
                    short8 a0 = ldc16(a0p + kc * 32);
                    short8 a1 = ldc16(a1p + kc * 32);
                    short8 b = *(const short8*)&ldsBc[l16 * 1032 + 512 + kc * 32 + quad * 8];
                    acc0 = __builtin_amdgcn_mfma_f32_16x16x32_bf16(a0, b, acc0, 0, 0, 0);
                    acc1 = __builtin_amdgcn_mfma_f32_16x16x32_bf16(a1, b, acc1, 0, 0, 0);
                }
            }
            float bp = biasp[nb + l16];
            float* ms = scr + wave * 256;
#pragma unroll
            for (int tt = 0; tt < 2; ++tt) {
                __syncthreads();                       // scr reuse fence
                int Mb = r0 + tt * 16;
#pragma unroll
                for (int r4 = 0; r4 < 4; ++r4) {
                    float g = (tt ? acc1[r4] : acc0[r4]) + bp;
                    ms[(quad * 4 + r4) * 16 + l16] = g;
                }
                __syncthreads();                       // writes visible
                int rloc = lane >> 2, u = lane & 3;
                float gi = ms[rloc * 16 + u * 4 + 0];
                float gf = ms[rloc * 16 + u * 4 + 1];
                float gg = ms[rloc * 16 + u * 4 + 2];
                float go = ms[rloc * 16 + u * 4 + 3];
                int b = Mb + rloc;
                int j = (nb >> 2) + u;
                float cold = tt ? creg1 : creg0;
                float cn = sigm(gf) * cold + sigm(gi) * tanhf(gg);
                float hn = sigm(go) * tanhf(cn);
                if (tt) creg1 = cn; else creg0 = cn;
                if (t < T_ - 1) {
                    float gv = bf2f(gh[((size_t)b * T_ + t + 1) * 512 + j]);
                    st_bf16_wt(&hdW[(size_t)b * 512 + j], f2bf(hn * gv));
                } else {
                    out[6553600 + (size_t)b * 512 + j] = hn;   // final h (kernel-end flush)
                }
            }
        }
        gbar(cnt2, (unsigned)(2 * t + 2) * 256u);
    }

    // ---- finalize ----
    if (wg == 0) {
        float v = 0.f;
        if (tid < T_) {
            float s = 0.f;
            for (int w = 0; w < 64; ++w) s += ldcf(&num2[tid * 64 + w]);
            v = s / (den[tid] + 1e-9f);
        }
        scr[tid] = v;
        __syncthreads();
        for (int s = 128; s > 0; s >>= 1) { if (tid < s) scr[tid] += scr[tid + s]; __syncthreads(); }
        if (tid == 0) out[6684672] = scr[0] / 300.0f;
    }
}

extern "C" void kernel_launch(void* const* d_in, const int* in_sizes, int n_in,
                              void* d_out, int out_size, void* d_ws, size_t ws_size,
                              hipStream_t stream) {
    (void)in_sizes; (void)n_in; (void)out_size; (void)ws_size;
    const float* values = (const float*)d_in[0];
    const float* masks  = (const float*)d_in[1];
    const float* deltas = (const float*)d_in[2];
    const float* W_td_h = (const float*)d_in[3];
    const float* b_td_h = (const float*)d_in[4];
    const float* W_td_x = (const float*)d_in[5];
    const float* b_td_x = (const float*)d_in[6];
    const float* W_hist = (const float*)d_in[7];
    const float* b_hist = (const float*)d_in[8];
    const float* W_feat = (const float*)d_in[9];
    const float* b_feat = (const float*)d_in[10];
    const float* W_comb = (const float*)d_in[11];
    const float* b_comb = (const float*)d_in[12];
    const float* W_ih   = (const float*)d_in[13];
    const float* W_hh   = (const float*)d_in[14];
    const float* b_ih   = (const float*)d_in[15];
    const float* b_hh   = (const float*)d_in[16];

    unsigned char* wsb = (unsigned char*)d_ws;
    float* out = (float*)d_out;

    k_init2<<<1280, 256, 0, stream>>>(wsb);
    k_prep2<<<2048, 256, 0, stream>>>(W_ih, W_hh, b_ih, b_hh, W_hist, W_feat, wsb);
    k_den<<<100, 256, 0, stream>>>(masks, wsb);
    k_maskt<<<6400, 256, 0, stream>>>(masks, wsb);
    k_gamma_h<<<dim3(400, 8), 256, 0, stream>>>(deltas, W_td_h, b_td_h, wsb);
    k_alpha<<<dim3(400, 4), 256, 0, stream>>>(deltas, masks, W_td_x, b_td_x, W_comb, b_comb, wsb);
    k_persist<<<256, 256, 0, stream>>>(values, masks, b_hist, b_feat, out, wsb);
}

// Round 4
// 2865.244 us; speedup vs baseline: 10.2356x; 1.4766x over previous
//
#include <hip/hip_runtime.h>
#include <math.h>

// RITS recurrent imputation. B=256, T=100, F=256, H=512.
// Round 6: column-parallel persistent kernel.
//  - Cross-wg data: write-through-to-LLC stores (sc0 sc1) + PLAIN CACHED reads;
//    coherence via one acquire fence (L1+L2 inv) per barrier, after release.
//    L2 re-absorbs shared operands per phase (vs round 5's per-wg MALL reads).
//  - Private-flag barrier: last arriver fans out per-wg go-flags (64B-spaced
//    lines); each wg polls only its own flag -> no poll contention.
//  - Phase C retile: wg = 64 rows x 32 packed cols (was 128x16): halves
//    shared-operand traffic, one A-load feeds two MFMAs. Bc LDS slice 66 KB.
//  - Wave-private gate scratch (no syncthreads in epilogue).
// MFMA chain order per output unchanged (ccb -> mt -> hd): bit-identical math.

#define T_ 100

typedef unsigned short ushortT;
typedef __attribute__((ext_vector_type(8))) short short8;
typedef __attribute__((ext_vector_type(4))) float f32x4;

// ---- workspace byte offsets ----
#define OB_HD0    1048576u    // bf16 hdec buf0 [256*512]
#define OB_HD1    1310720u    // bf16 hdec buf1
#define OB_XCB    1835008u    // bf16 x_c
#define OB_CCB    1966080u    // bf16 c_c
#define OB_NUM2   2097152u    // fp32 [100*64] loss partials
#define OB_DEN    2122752u    // fp32 [128]
#define OB_CNT    2123264u    // u32 full-barrier counter; +128: 64-wg counter
#define OB_BIASP  2123776u    // fp32 [2048] packed b_ih+b_hh
#define OB_BA     2131968u    // bf16 W_hist [256*512]
#define OB_BB     2394112u    // bf16 Wf masked [256*256]
#define OB_BC     2525184u    // bf16 packed [2048*1024] = [wihp|whhp]
#define OB_MT     6719488u    // bf16 masks time-major [100*256*256]
#define OB_GH     19826688u   // bf16 gamma_h [25600*512]
#define OB_AL     46041088u   // bf16 alpha [25600*256]
#define OB_FLG1   59148288u   // u32 go-flags, 64 wgs x 16 dwords (64B lines)
#define OB_FLG2   59152384u   // u32 go-flags, 256 wgs x 16 dwords
// end 59,168,768 B < ws_size

__device__ __forceinline__ float sigm(float x) { return 1.0f / (1.0f + expf(-x)); }

__device__ __forceinline__ ushortT f2bf(float f) {
    union { float f; unsigned u; } v; v.f = f;
    unsigned r = v.u + 0x7fffu + ((v.u >> 16) & 1u);   // RNE
    return (ushortT)(r >> 16);
}
__device__ __forceinline__ float bf2f(ushortT h) {
    union { unsigned u; float f; } v; v.u = ((unsigned)h) << 16; return v.f;
}

// write-through-to-LLC stores: once vmcnt retires they are at the coherence point.
__device__ __forceinline__ void st_bf16_wt(ushortT* p, ushortT v) {
    asm volatile("global_store_short %0, %1, off sc0 sc1" :: "v"(p), "v"((unsigned)v) : "memory");
}
__device__ __forceinline__ void st_f32_wt(float* p, float v) {
    asm volatile("global_store_dword %0, %1, off sc0 sc1" :: "v"(p), "v"(v) : "memory");
}
__device__ __forceinline__ void st_u32_wt(unsigned* p, unsigned v) {
    asm volatile("global_store_dword %0, %1, off sc0 sc1" :: "v"(p), "v"(v) : "memory");
}

// Barrier: drain wt stores -> arrive (relaxed agent add). The LAST arriver
// fans out per-wg go-flags (one 64B line each); everyone else polls only its
// own flag. Then ONE acquire fence (L1+L2 inv) before any cross-wg read.
__device__ __forceinline__ void gbar(unsigned* cnt, unsigned* flags, unsigned epoch,
                                     unsigned nwg, unsigned myid, unsigned* rel) {
    asm volatile("s_waitcnt vmcnt(0)" ::: "memory");   // wt stores at LLC (all waves)
    __syncthreads();
    if (threadIdx.x == 0) {
        unsigned old = __hip_atomic_fetch_add(cnt, 1u, __ATOMIC_RELAXED, __HIP_MEMORY_SCOPE_AGENT);
        *rel = (old == epoch * nwg - 1u) ? 1u : 0u;
    }
    __syncthreads();
    if (*rel) {
        if (threadIdx.x < nwg) st_u32_wt(&flags[threadIdx.x * 16], epoch);
    } else if (threadIdx.x == 0) {
        while (__hip_atomic_load(&flags[myid * 16], __ATOMIC_RELAXED, __HIP_MEMORY_SCOPE_AGENT) < epoch)
            __builtin_amdgcn_s_sleep(8);
    }
    if (threadIdx.x == 0)
        __builtin_amdgcn_fence(__ATOMIC_ACQUIRE, "agent");   // inv L1 + this XCD's L2
    __syncthreads();
}

// ---------------- prep kernels (identical numerics) ----------------

__global__ __launch_bounds__(256) void k_init2(unsigned char* wsb) {
    unsigned i = blockIdx.x * 256u + threadIdx.x;   // 1300 blocks
    unsigned* w = (unsigned*)wsb;
    if (i < 327680u) w[i] = 0u;                     // hdec buf0 (+ legacy range)
    else if (i < 332800u) ((unsigned*)(wsb + OB_FLG1))[i - 327680u] = 0u;  // flags (20KB)
    if (i == 0) {
        *(unsigned*)(wsb + OB_CNT) = 0u;
        *(unsigned*)(wsb + OB_CNT + 128) = 0u;
    }
}

__global__ __launch_bounds__(256) void k_prep2(const float* __restrict__ W_ih,
                                               const float* __restrict__ W_hh,
                                               const float* __restrict__ b_ih,
                                               const float* __restrict__ b_hh,
                                               const float* __restrict__ W_hist,
                                               const float* __restrict__ W_feat,
                                               unsigned char* wsb) {
    ushortT* Bc = (ushortT*)(wsb + OB_BC);
    ushortT* Ba = (ushortT*)(wsb + OB_BA);
    ushortT* Bb = (ushortT*)(wsb + OB_BB);
    float* biasp = (float*)(wsb + OB_BIASP);
    int n = blockIdx.x;                  // packed row, n = 4*j + g
    int j = n >> 2, g = n & 3;
    int src = g * 512 + j;
    for (int k = threadIdx.x; k < 512; k += 256) {
        Bc[(size_t)n * 1024 + k]       = f2bf(W_ih[(size_t)src * 512 + k]);
        Bc[(size_t)n * 1024 + 512 + k] = f2bf(W_hh[(size_t)src * 512 + k]);
        if (n < 256) {
            Ba[(size_t)n * 512 + k] = f2bf(W_hist[(size_t)n * 512 + k]);
            if (k < 256) Bb[(size_t)n * 256 + k] = (k == n) ? 0 : f2bf(W_feat[(size_t)n * 256 + k]);
        }
    }
    if (threadIdx.x == 0) biasp[n] = b_ih[src] + b_hh[src];
}

__global__ __launch_bounds__(256) void k_den(const float* __restrict__ masks, unsigned char* wsb) {
    __shared__ float red[256];
    float* den = (float*)(wsb + OB_DEN);
    int t = blockIdx.x;
    float s = 0.0f;
    for (int idx = threadIdx.x; idx < 256 * 256; idx += 256) {
        int b = idx >> 8, f = idx & 255;
        s += masks[((size_t)b * T_ + t) * 256 + f];
    }
    red[threadIdx.x] = s; __syncthreads();
    for (int st = 128; st > 0; st >>= 1) { if (threadIdx.x < st) red[threadIdx.x] += red[threadIdx.x + st]; __syncthreads(); }
    if (threadIdx.x == 0) den[t] = red[0];
}

__global__ __launch_bounds__(256) void k_maskt(const float* __restrict__ masks, unsigned char* wsb) {
    ushortT* mt = (ushortT*)(wsb + OB_MT);
    unsigned gidx = blockIdx.x * 256u + threadIdx.x;   // 6400 blocks -> 1,638,400
    int f4 = gidx & 63;
    unsigned rest = gidx >> 6;                          // 0..25599
    int t = rest % 100, b = rest / 100;
    float4 m = *(const float4*)(masks + ((size_t)b * T_ + t) * 256 + f4 * 4);
    size_t o = ((size_t)t * 256 + b) * 256 + f4 * 4;
    mt[o + 0] = f2bf(m.x); mt[o + 1] = f2bf(m.y); mt[o + 2] = f2bf(m.z); mt[o + 3] = f2bf(m.w);
}

// gamma_h: [25600,512] = exp(-relu(D @ W_td_h.T + b)), K=256 (fp32 tile GEMM)
__global__ __launch_bounds__(256) void k_gamma_h(const float* __restrict__ deltas,
                                                 const float* __restrict__ W,
                                                 const float* __restrict__ bias,
                                                 unsigned char* wsb) {
    ushortT* gh = (ushortT*)(wsb + OB_GH);
    __shared__ float As[16][65];
    __shared__ float Bs[16][65];
    int tid = threadIdx.x;
    int tx = tid & 15, ty = tid >> 4;
    int mb = blockIdx.x * 64, nb = blockIdx.y * 64;
    int lr = tid >> 2, lk = (tid & 3) * 4;
    float acc[4][4] = {};
    for (int k0 = 0; k0 < 256; k0 += 16) {
        float4 a = *(const float4*)(deltas + (size_t)(mb + lr) * 256 + k0 + lk);
        float4 b = *(const float4*)(W + (size_t)(nb + lr) * 256 + k0 + lk);
        As[lk + 0][lr] = a.x; As[lk + 1][lr] = a.y; As[lk + 2][lr] = a.z; As[lk + 3][lr] = a.w;
        Bs[lk + 0][lr] = b.x; Bs[lk + 1][lr] = b.y; Bs[lk + 2][lr] = b.z; Bs[lk + 3][lr] = b.w;
        __syncthreads();
#pragma unroll
        for (int kk = 0; kk < 16; kk++) {
            float av[4], bv[4];
#pragma unroll
            for (int i = 0; i < 4; i++) av[i] = As[kk][ty * 4 + i];
#pragma unroll
            for (int j = 0; j < 4; j++) bv[j] = Bs[kk][tx * 4 + j];
#pragma unroll
            for (int i = 0; i < 4; i++)
#pragma unroll
                for (int j = 0; j < 4; j++) acc[i][j] = fmaf(av[i], bv[j], acc[i][j]);
        }
        __syncthreads();
    }
#pragma unroll
    for (int i = 0; i < 4; i++) {
        int r = mb + ty * 4 + i;
#pragma unroll
        for (int j = 0; j < 4; j++) {
            int n = nb + tx * 4 + j;
            float v = acc[i][j] + bias[n];
            gh[(size_t)r * 512 + n] = f2bf(expf(-fmaxf(v, 0.0f)));
        }
    }
}

// alpha: [25600,256] = sigmoid([gamma_x|m] @ W_comb.T + b), K=512
__global__ __launch_bounds__(256) void k_alpha(const float* __restrict__ deltas,
                                               const float* __restrict__ masks,
                                               const float* __restrict__ Wtdx,
                                               const float* __restrict__ btdx,
                                               const float* __restrict__ Wc,
                                               const float* __restrict__ bc,
                                               unsigned char* wsb) {
    ushortT* al = (ushortT*)(wsb + OB_AL);
    __shared__ float As[16][65];
    __shared__ float Bs[16][65];
    int tid = threadIdx.x;
    int tx = tid & 15, ty = tid >> 4;
    int mb = blockIdx.x * 64, nb = blockIdx.y * 64;
    int lr = tid >> 2, lk = (tid & 3) * 4;
    float acc[4][4] = {};
    for (int k0 = 0; k0 < 512; k0 += 16) {
        int kg = k0 + lk;
        float4 a;
        if (kg < 256) {
            float4 d4 = *(const float4*)(deltas + (size_t)(mb + lr) * 256 + kg);
            a.x = expf(-fmaxf(d4.x * Wtdx[(size_t)(kg + 0) * 257] + btdx[kg + 0], 0.0f));
            a.y = expf(-fmaxf(d4.y * Wtdx[(size_t)(kg + 1) * 257] + btdx[kg + 1], 0.0f));
            a.z = expf(-fmaxf(d4.z * Wtdx[(size_t)(kg + 2) * 257] + btdx[kg + 2], 0.0f));
            a.w = expf(-fmaxf(d4.w * Wtdx[(size_t)(kg + 3) * 257] + btdx[kg + 3], 0.0f));
        } else {
            a = *(const float4*)(masks + (size_t)(mb + lr) * 256 + (kg - 256));
        }
        float4 b = *(const float4*)(Wc + (size_t)(nb + lr) * 512 + kg);
        As[lk + 0][lr] = a.x; As[lk + 1][lr] = a.y; As[lk + 2][lr] = a.z; As[lk + 3][lr] = a.w;
        Bs[lk + 0][lr] = b.x; Bs[lk + 1][lr] = b.y; Bs[lk + 2][lr] = b.z; Bs[lk + 3][lr] = b.w;
        __syncthreads();
#pragma unroll
        for (int kk = 0; kk < 16; kk++) {
            float av[4], bv[4];
#pragma unroll
            for (int i = 0; i < 4; i++) av[i] = As[kk][ty * 4 + i];
#pragma unroll
            for (int j = 0; j < 4; j++) bv[j] = Bs[kk][tx * 4 + j];
#pragma unroll
            for (int i = 0; i < 4; i++)
#pragma unroll
                for (int j = 0; j < 4; j++) acc[i][j] = fmaf(av[i], bv[j], acc[i][j]);
        }
        __syncthreads();
    }
#pragma unroll
    for (int i = 0; i < 4; i++) {
        int r = mb + ty * 4 + i;
#pragma unroll
        for (int j = 0; j < 4; j++) {
            int n = nb + tx * 4 + j;
            al[(size_t)r * 256 + n] = f2bf(sigm(acc[i][j] + bc[n]));
        }
    }
}

// ---------------- persistent kernel ----------------

__global__ __launch_bounds__(256, 1) void k_persist(const float* __restrict__ values,
                                                    const float* __restrict__ masks,
                                                    const float* __restrict__ b_hist,
                                                    const float* __restrict__ b_feat,
                                                    float* __restrict__ out,
                                                    unsigned char* __restrict__ wsb) {
    ushortT* hd[2] = { (ushortT*)(wsb + OB_HD0), (ushortT*)(wsb + OB_HD1) };
    ushortT* xcb = (ushortT*)(wsb + OB_XCB);
    ushortT* ccb = (ushortT*)(wsb + OB_CCB);
    float* num2 = (float*)(wsb + OB_NUM2);
    const float* den = (const float*)(wsb + OB_DEN);
    unsigned* cnt2 = (unsigned*)(wsb + OB_CNT);
    unsigned* cnt1 = (unsigned*)(wsb + OB_CNT + 128);
    unsigned* flg1 = (unsigned*)(wsb + OB_FLG1);
    unsigned* flg2 = (unsigned*)(wsb + OB_FLG2);
    const float* biasp = (const float*)(wsb + OB_BIASP);
    const ushortT* Ba = (const ushortT*)(wsb + OB_BA);
    const ushortT* Bb = (const ushortT*)(wsb + OB_BB);
    const ushortT* Bc = (const ushortT*)(wsb + OB_BC);
    const ushortT* mt = (const ushortT*)(wsb + OB_MT);
    const ushortT* gh = (const ushortT*)(wsb + OB_GH);
    const ushortT* al = (const ushortT*)(wsb + OB_AL);

    __shared__ ushortT ldsBc[32 * 1032];   // 66048 B: 32 packed-gate rows x 1024 (+8 pad)
    __shared__ ushortT ldsBa[16 * 520];    // 16640 B
    __shared__ ushortT ldsBb[16 * 264];    //  8448 B
    __shared__ float scr[4 * 16 * 36];     //  9216 B: per-wave gate scratch [16][36]
    __shared__ float lossSlots[8];
    __shared__ unsigned relsh;

    const int wg = blockIdx.x, tid = threadIdx.x;
    const int wave = tid >> 6, lane = tid & 63, quad = lane >> 4, l16 = lane & 15;

    // ---- load LDS weight slices (once) ----
    {
        int n0 = (wg & 63) * 32;                      // phase C: 32 packed rows
        for (int i = tid; i < 4096; i += 256) {       // 32 rows x 128 chunks of 8
            int r = i >> 7, c = i & 127;
            *(short8*)&ldsBc[r * 1032 + c * 8] = *(const short8*)&Bc[(size_t)(n0 + r) * 1024 + c * 8];
        }
        if (wg < 64) {
            int nA = (wg & 15) * 16;
            for (int i = tid; i < 1024; i += 256) {   // 16 x 64
                int r = i >> 6, c = i & 63;
                *(short8*)&ldsBa[r * 520 + c * 8] = *(const short8*)&Ba[(size_t)(nA + r) * 512 + c * 8];
            }
            for (int i = tid; i < 512; i += 256) {    // 16 x 32
                int r = i >> 5, c = i & 31;
                *(short8*)&ldsBb[r * 264 + c * 8] = *(const short8*)&Bb[(size_t)(nA + r) * 256 + c * 8];
            }
        }
        __syncthreads();
    }

    // phase C t-invariant per-thread mapping
    const int rgC = wg >> 6, cgC = wg & 63;
    const int r0C = rgC * 64 + wave * 16;             // wave's 16 rows
    const int n0C = cgC * 32;                          // 32 packed cols
    const float bp0 = biasp[n0C + l16];
    const float bp1 = biasp[n0C + 16 + l16];
    const int rowl = lane >> 2, q4 = lane & 3;        // epilogue cell mapping
    const int bbE = rgC * 64 + wave * 16 + rowl;
    const int j0E = cgC * 8 + q4, j1E = j0E + 4;
    float creg0 = 0.f, creg1 = 0.f;

#pragma unroll 1
    for (int t = 0; t < T_; ++t) {
        const ushortT* hdA = hd[t & 1];
        ushortT* hdW = hd[(t + 1) & 1];

        if (wg < 64) {
            int mb = (wg >> 4) * 64, nb = (wg & 15) * 16;
            int rowA = mb + wave * 16;
            int n = nb + l16;
            float xhv[4];                  // x_h stays in registers across A->B

            // ---- phase A: x_h = hdec @ W_hist.T ----
            {
                f32x4 acc = {0.f, 0.f, 0.f, 0.f};
                const ushortT* aBase = hdA + (size_t)(rowA + l16) * 512 + quad * 8;
#pragma unroll 8
                for (int kc = 0; kc < 16; ++kc) {
                    short8 a = *(const short8*)(aBase + kc * 32);
                    short8 b = *(const short8*)&ldsBa[l16 * 520 + kc * 32 + quad * 8];
                    acc = __builtin_amdgcn_mfma_f32_16x16x32_bf16(a, b, acc, 0, 0, 0);
                }
                float bh = b_hist[n];
                float ls = 0.f;
#pragma unroll
                for (int r4 = 0; r4 < 4; ++r4) {
                    int r = rowA + quad * 4 + r4;
                    float v = acc[r4] + bh;
                    xhv[r4] = v;
                    size_t idx = ((size_t)r * T_ + t) * 256 + n;
                    float x = values[idx], m = masks[idx];
                    st_bf16_wt(&xcb[r * 256 + n], f2bf(m * x + (1.f - m) * v));
                    ls += fabsf(v - x) * m;
                }
                for (int off = 32; off; off >>= 1) ls += __shfl_down(ls, off);
                if (lane == 0) lossSlots[wave] = ls;
            }
            gbar(cnt1, flg1, (unsigned)(t + 1), 64u, (unsigned)wg, &relsh);

            // ---- phase B: z_h = x_c @ Wf.T; c_h, c_c, losses ----
            {
                f32x4 acc = {0.f, 0.f, 0.f, 0.f};
                const ushortT* aBase = xcb + (size_t)(rowA + l16) * 256 + quad * 8;
#pragma unroll
                for (int kc = 0; kc < 8; ++kc) {
                    short8 a = *(const short8*)(aBase + kc * 32);
                    short8 b = *(const short8*)&ldsBb[l16 * 264 + kc * 32 + quad * 8];
                    acc = __builtin_amdgcn_mfma_f32_16x16x32_bf16(a, b, acc, 0, 0, 0);
                }
                float bfv = b_feat[n];
                float ls = 0.f;
#pragma unroll
                for (int r4 = 0; r4 < 4; ++r4) {
                    int r = rowA + quad * 4 + r4;
                    float z = fmaxf(acc[r4] + bfv, 0.f);
                    size_t idx = ((size_t)r * T_ + t) * 256 + n;
                    float a_ = bf2f(al[idx]);
                    float ch = a_ * z + (1.f - a_) * xhv[r4];
                    float x = values[idx], m = masks[idx];
                    float ccv = m * x + (1.f - m) * ch;
                    out[idx] = ccv;                       // imputed[:,t,:] == c_c
                    st_bf16_wt(&ccb[r * 256 + n], f2bf(ccv));
                    ls += (fabsf(z - x) + fabsf(ch - x)) * m;
                }
                for (int off = 32; off; off >>= 1) ls += __shfl_down(ls, off);
                if (lane == 0) lossSlots[4 + wave] = ls;
                __syncthreads();
                if (tid == 0) {
                    float s = 0.f;
                    for (int i = 0; i < 8; ++i) s += lossSlots[i];
                    st_f32_wt(&num2[t * 64 + wg], s);
                }
            }
        }
        gbar(cnt2, flg2, (unsigned)(2 * t + 1), 256u, (unsigned)wg, &relsh);

        // ---- phase C: gates[64 rows x 32 cols] = [cc|m|hdec] @ BcT (K=1024) ----
        {
            f32x4 acc0 = {0.f, 0.f, 0.f, 0.f}, acc1 = {0.f, 0.f, 0.f, 0.f};
            const int lb0 = l16 * 1032 + quad * 8;
            const int lb1 = (16 + l16) * 1032 + quad * 8;
            {   // seg0: K 0..255 from ccb
                const ushortT* ap = ccb + (size_t)(r0C + l16) * 256 + quad * 8;
#pragma unroll
                for (int kc = 0; kc < 8; ++kc) {
                    short8 a  = *(const short8*)(ap + kc * 32);
                    short8 b0 = *(const short8*)&ldsBc[lb0 + kc * 32];
                    short8 b1 = *(const short8*)&ldsBc[lb1 + kc * 32];
                    acc0 = __builtin_amdgcn_mfma_f32_16x16x32_bf16(a, b0, acc0, 0, 0, 0);
                    acc1 = __builtin_amdgcn_mfma_f32_16x16x32_bf16(a, b1, acc1, 0, 0, 0);
                }
            }
            {   // seg1: K 256..511 from mt (read-only)
                const ushortT* ap = mt + (size_t)t * 65536 + (size_t)(r0C + l16) * 256 + quad * 8;
#pragma unroll
                for (int kc = 0; kc < 8; ++kc) {
                    short8 a  = *(const short8*)(ap + kc * 32);
                    short8 b0 = *(const short8*)&ldsBc[lb0 + 256 + kc * 32];
                    short8 b1 = *(const short8*)&ldsBc[lb1 + 256 + kc * 32];
                    acc0 = __builtin_amdgcn_mfma_f32_16x16x32_bf16(a, b0, acc0, 0, 0, 0);
                    acc1 = __builtin_amdgcn_mfma_f32_16x16x32_bf16(a, b1, acc1, 0, 0, 0);
                }
            }
            {   // seg2: K 512..1023 from hdec
                const ushortT* ap = hdA + (size_t)(r0C + l16) * 512 + quad * 8;
#pragma unroll 8
                for (int kc = 0; kc < 16; ++kc) {
                    short8 a  = *(const short8*)(ap + kc * 32);
                    short8 b0 = *(const short8*)&ldsBc[lb0 + 512 + kc * 32];
                    short8 b1 = *(const short8*)&ldsBc[lb1 + 512 + kc * 32];
                    acc0 = __builtin_amdgcn_mfma_f32_16x16x32_bf16(a, b0, acc0, 0, 0, 0);
                    acc1 = __builtin_amdgcn_mfma_f32_16x16x32_bf16(a, b1, acc1, 0, 0, 0);
                }
            }

            // ---- epilogue: wave-private gate exchange + LSTM ----
            float* ms = scr + wave * (16 * 36);
#pragma unroll
            for (int r4 = 0; r4 < 4; ++r4) {
                ms[(quad * 4 + r4) * 36 + l16]      = acc0[r4] + bp0;
                ms[(quad * 4 + r4) * 36 + 16 + l16] = acc1[r4] + bp1;
            }
            // same-wave LDS ordering: compiler orders write->read via lgkmcnt
            const float* g0 = &ms[rowl * 36 + q4 * 4];
            const float* g1 = &ms[rowl * 36 + 16 + q4 * 4];
            float cn0 = sigm(g0[1]) * creg0 + sigm(g0[0]) * tanhf(g0[2]);
            float hn0 = sigm(g0[3]) * tanhf(cn0);
            float cn1 = sigm(g1[1]) * creg1 + sigm(g1[0]) * tanhf(g1[2]);
            float hn1 = sigm(g1[3]) * tanhf(cn1);
            creg0 = cn0; creg1 = cn1;
            if (t < T_ - 1) {
                float gv0 = bf2f(gh[((size_t)bbE * T_ + t + 1) * 512 + j0E]);
                float gv1 = bf2f(gh[((size_t)bbE * T_ + t + 1) * 512 + j1E]);
                st_bf16_wt(&hdW[(size_t)bbE * 512 + j0E], f2bf(hn0 * gv0));
                st_bf16_wt(&hdW[(size_t)bbE * 512 + j1E], f2bf(hn1 * gv1));
            } else {
                out[6553600 + (size_t)bbE * 512 + j0E] = hn0;
                out[6553600 + (size_t)bbE * 512 + j1E] = hn1;
            }
        }
        gbar(cnt2, flg2, (unsigned)(2 * t + 2), 256u, (unsigned)wg, &relsh);
    }

    // ---- finalize ----
    if (wg == 0) {
        float v = 0.f;
        if (tid < T_) {
            float s = 0.f;
            for (int w = 0; w < 64; ++w) s += num2[tid * 64 + w];
            v = s / (den[tid] + 1e-9f);
        }
        scr[tid] = v;
        __syncthreads();
        for (int s = 128; s > 0; s >>= 1) { if (tid < s) scr[tid] += scr[tid + s]; __syncthreads(); }
        if (tid == 0) out[6684672] = scr[0] / 300.0f;
    }
}

extern "C" void kernel_launch(void* const* d_in, const int* in_sizes, int n_in,
                              void* d_out, int out_size, void* d_ws, size_t ws_size,
                              hipStream_t stream) {
    (void)in_sizes; (void)n_in; (void)out_size; (void)ws_size;
    const float* values = (const float*)d_in[0];
    const float* masks  = (const float*)d_in[1];
    const float* deltas = (const float*)d_in[2];
    const float* W_td_h = (const float*)d_in[3];
    const float* b_td_h = (const float*)d_in[4];
    const float* W_td_x = (const float*)d_in[5];
    const float* b_td_x = (const float*)d_in[6];
    const float* W_hist = (const float*)d_in[7];
    const float* b_hist = (const float*)d_in[8];
    const float* W_feat = (const float*)d_in[9];
    const float* b_feat = (const float*)d_in[10];
    const float* W_comb = (const float*)d_in[11];
    const float* b_comb = (const float*)d_in[12];
    const float* W_ih   = (const float*)d_in[13];
    const float* W_hh   = (const float*)d_in[14];
    const float* b_ih   = (const float*)d_in[15];
    const float* b_hh   = (const float*)d_in[16];

    unsigned char* wsb = (unsigned char*)d_ws;
    float* out = (float*)d_out;

    k_init2<<<1300, 256, 0, stream>>>(wsb);
    k_prep2<<<2048, 256, 0, stream>>>(W_ih, W_hh, b_ih, b_hh, W_hist, W_feat, wsb);
    k_den<<<100, 256, 0, stream>>>(masks, wsb);
    k_maskt<<<6400, 256, 0, stream>>>(masks, wsb);
    k_gamma_h<<<dim3(400, 8), 256, 0, stream>>>(deltas, W_td_h, b_td_h, wsb);
    k_alpha<<<dim3(400, 4), 256, 0, stream>>>(deltas, masks, W_td_x, b_td_x, W_comb, b_comb, wsb);
    k_persist<<<256, 256, 0, stream>>>(values, masks, b_hist, b_feat, out, wsb);
}

// Round 5
// 2619.222 us; speedup vs baseline: 11.1970x; 1.0939x over previous
//
#include <hip/hip_runtime.h>
#include <math.h>

// RITS recurrent imputation. B=256, T=100, F=256, H=512.
// Round 7: 4 INDEPENDENT 64-wg domains (d = wg&3; batch rows d*64..d*64+63).
// All cross-wg dataflow (hd, xcb, ccb) is domain-closed -> domain-local
// barriers only. Barriers are flag arrays: producer wt-stores epoch to its own
// slot; consumer wave0 polls slots with per-lane agent atomic loads + __all;
// one acquire fence after a successful wait. No atomic-counter serialization,
// no fan-out hop. Phase C's mt+hd segments (24/32 MFMAs) hoisted BEFORE the
// B->C barrier (gate accum order now mt->hd->ccb). values/masks held in regs
// across A->B.

#define T_ 100

typedef unsigned short ushortT;
typedef __attribute__((ext_vector_type(8))) short short8;
typedef __attribute__((ext_vector_type(4))) float f32x4;

// ---- workspace byte offsets ----
#define OB_HD0    1048576u    // bf16 hdec buf0 [256*512]
#define OB_HD1    1310720u    // bf16 hdec buf1
#define OB_XCB    1835008u    // bf16 x_c
#define OB_CCB    1966080u    // bf16 c_c
#define OB_NUM2   2097152u    // fp32 [100*64] loss partials
#define OB_DEN    2122752u    // fp32 [128]
#define OB_BIASP  2123776u    // fp32 [2048] packed b_ih+b_hh
#define OB_BA     2131968u    // bf16 W_hist [256*512]
#define OB_BB     2394112u    // bf16 Wf masked [256*256]
#define OB_BC     2525184u    // bf16 packed [2048*1024] = [wihp|whhp]
#define OB_MT     6719488u    // bf16 masks time-major [100*256*256]
#define OB_GH     19826688u   // bf16 gamma_h [25600*512]
#define OB_AL     46041088u   // bf16 alpha [25600*256]
#define OB_FLG    59148288u   // u32 flags: fA[4][64], fB[4][64], fC[4][64], cntF

__device__ __forceinline__ float sigm(float x) { return 1.0f / (1.0f + expf(-x)); }

__device__ __forceinline__ ushortT f2bf(float f) {
    union { float f; unsigned u; } v; v.f = f;
    unsigned r = v.u + 0x7fffu + ((v.u >> 16) & 1u);   // RNE
    return (ushortT)(r >> 16);
}
__device__ __forceinline__ float bf2f(ushortT h) {
    union { unsigned u; float f; } v; v.u = ((unsigned)h) << 16; return v.f;
}

// write-through-to-LLC stores: once vmcnt retires they are at the coherence point.
__device__ __forceinline__ void st_bf16_wt(ushortT* p, ushortT v) {
    asm volatile("global_store_short %0, %1, off sc0 sc1" :: "v"(p), "v"((unsigned)v) : "memory");
}
__device__ __forceinline__ void st_f32_wt(float* p, float v) {
    asm volatile("global_store_dword %0, %1, off sc0 sc1" :: "v"(p), "v"(v) : "memory");
}
__device__ __forceinline__ void st_u32_wt(unsigned* p, unsigned v) {
    asm volatile("global_store_dword %0, %1, off sc0 sc1" :: "v"(p), "v"(v) : "memory");
}

// arrive: drain this wg's wt stores to LLC, then publish epoch in own slot.
__device__ __forceinline__ void bar_arrive(unsigned* slot, unsigned epoch) {
    asm volatile("s_waitcnt vmcnt(0)" ::: "memory");
    __syncthreads();
    if (threadIdx.x == 0) st_u32_wt(slot, epoch);
}

// wait: wave0 lanes poll one slot each (agent loads bypass stale L1/L2);
// after all slots reach epoch, one acquire fence (inv) covers the wg's reads.
__device__ __forceinline__ void bar_wait(const unsigned* flags, unsigned nf, unsigned epoch) {
    if (threadIdx.x < 64) {
        for (;;) {
            unsigned f = epoch;
            if (threadIdx.x < nf)
                f = __hip_atomic_load(flags + threadIdx.x, __ATOMIC_RELAXED, __HIP_MEMORY_SCOPE_AGENT);
            if (__all((int)(f >= epoch))) break;
            __builtin_amdgcn_s_sleep(2);
        }
        if (threadIdx.x == 0)
            __builtin_amdgcn_fence(__ATOMIC_ACQUIRE, "agent");
    }
    __syncthreads();
}

// ---------------- prep kernels (identical numerics) ----------------

__global__ __launch_bounds__(256) void k_init2(unsigned char* wsb) {
    unsigned i = blockIdx.x * 256u + threadIdx.x;   // 256 blocks
    if (i < 65536u) ((unsigned*)(wsb + OB_HD0))[i] = 0u;   // hdec buf0
    if (i < 1024u)  ((unsigned*)(wsb + OB_FLG))[i] = 0u;   // flags + cntF
}

__global__ __launch_bounds__(256) void k_prep2(const float* __restrict__ W_ih,
                                               const float* __restrict__ W_hh,
                                               const float* __restrict__ b_ih,
                                               const float* __restrict__ b_hh,
                                               const float* __restrict__ W_hist,
                                               const float* __restrict__ W_feat,
                                               unsigned char* wsb) {
    ushortT* Bc = (ushortT*)(wsb + OB_BC);
    ushortT* Ba = (ushortT*)(wsb + OB_BA);
    ushortT* Bb = (ushortT*)(wsb + OB_BB);
    float* biasp = (float*)(wsb + OB_BIASP);
    int n = blockIdx.x;                  // packed row, n = 4*j + g
    int j = n >> 2, g = n & 3;
    int src = g * 512 + j;
    for (int k = threadIdx.x; k < 512; k += 256) {
        Bc[(size_t)n * 1024 + k]       = f2bf(W_ih[(size_t)src * 512 + k]);
        Bc[(size_t)n * 1024 + 512 + k] = f2bf(W_hh[(size_t)src * 512 + k]);
        if (n < 256) {
            Ba[(size_t)n * 512 + k] = f2bf(W_hist[(size_t)n * 512 + k]);
            if (k < 256) Bb[(size_t)n * 256 + k] = (k == n) ? 0 : f2bf(W_feat[(size_t)n * 256 + k]);
        }
    }
    if (threadIdx.x == 0) biasp[n] = b_ih[src] + b_hh[src];
}

__global__ __launch_bounds__(256) void k_den(const float* __restrict__ masks, unsigned char* wsb) {
    __shared__ float red[256];
    float* den = (float*)(wsb + OB_DEN);
    int t = blockIdx.x;
    float s = 0.0f;
    for (int idx = threadIdx.x; idx < 256 * 256; idx += 256) {
        int b = idx >> 8, f = idx & 255;
        s += masks[((size_t)b * T_ + t) * 256 + f];
    }
    red[threadIdx.x] = s; __syncthreads();
    for (int st = 128; st > 0; st >>= 1) { if (threadIdx.x < st) red[threadIdx.x] += red[threadIdx.x + st]; __syncthreads(); }
    if (threadIdx.x == 0) den[t] = red[0];
}

__global__ __launch_bounds__(256) void k_maskt(const float* __restrict__ masks, unsigned char* wsb) {
    ushortT* mt = (ushortT*)(wsb + OB_MT);
    unsigned gidx = blockIdx.x * 256u + threadIdx.x;   // 6400 blocks -> 1,638,400
    int f4 = gidx & 63;
    unsigned rest = gidx >> 6;                          // 0..25599
    int t = rest % 100, b = rest / 100;
    float4 m = *(const float4*)(masks + ((size_t)b * T_ + t) * 256 + f4 * 4);
    size_t o = ((size_t)t * 256 + b) * 256 + f4 * 4;
    mt[o + 0] = f2bf(m.x); mt[o + 1] = f2bf(m.y); mt[o + 2] = f2bf(m.z); mt[o + 3] = f2bf(m.w);
}

// gamma_h: [25600,512] = exp(-relu(D @ W_td_h.T + b)), K=256 (fp32 tile GEMM)
__global__ __launch_bounds__(256) void k_gamma_h(const float* __restrict__ deltas,
                                                 const float* __restrict__ W,
                                                 const float* __restrict__ bias,
                                                 unsigned char* wsb) {
    ushortT* gh = (ushortT*)(wsb + OB_GH);
    __shared__ float As[16][65];
    __shared__ float Bs[16][65];
    int tid = threadIdx.x;
    int tx = tid & 15, ty = tid >> 4;
    int mb = blockIdx.x * 64, nb = blockIdx.y * 64;
    int lr = tid >> 2, lk = (tid & 3) * 4;
    float acc[4][4] = {};
    for (int k0 = 0; k0 < 256; k0 += 16) {
        float4 a = *(const float4*)(deltas + (size_t)(mb + lr) * 256 + k0 + lk);
        float4 b = *(const float4*)(W + (size_t)(nb + lr) * 256 + k0 + lk);
        As[lk + 0][lr] = a.x; As[lk + 1][lr] = a.y; As[lk + 2][lr] = a.z; As[lk + 3][lr] = a.w;
        Bs[lk + 0][lr] = b.x; Bs[lk + 1][lr] = b.y; Bs[lk + 2][lr] = b.z; Bs[lk + 3][lr] = b.w;
        __syncthreads();
#pragma unroll
        for (int kk = 0; kk < 16; kk++) {
            float av[4], bv[4];
#pragma unroll
            for (int i = 0; i < 4; i++) av[i] = As[kk][ty * 4 + i];
#pragma unroll
            for (int j = 0; j < 4; j++) bv[j] = Bs[kk][tx * 4 + j];
#pragma unroll
            for (int i = 0; i < 4; i++)
#pragma unroll
                for (int j = 0; j < 4; j++) acc[i][j] = fmaf(av[i], bv[j], acc[i][j]);
        }
        __syncthreads();
    }
#pragma unroll
    for (int i = 0; i < 4; i++) {
        int r = mb + ty * 4 + i;
#pragma unroll
        for (int j = 0; j < 4; j++) {
            int n = nb + tx * 4 + j;
            float v = acc[i][j] + bias[n];
            gh[(size_t)r * 512 + n] = f2bf(expf(-fmaxf(v, 0.0f)));
        }
    }
}

// alpha: [25600,256] = sigmoid([gamma_x|m] @ W_comb.T + b), K=512
__global__ __launch_bounds__(256) void k_alpha(const float* __restrict__ deltas,
                                               const float* __restrict__ masks,
                                               const float* __restrict__ Wtdx,
                                               const float* __restrict__ btdx,
                                               const float* __restrict__ Wc,
                                               const float* __restrict__ bc,
                                               unsigned char* wsb) {
    ushortT* al = (ushortT*)(wsb + OB_AL);
    __shared__ float As[16][65];
    __shared__ float Bs[16][65];
    int tid = threadIdx.x;
    int tx = tid & 15, ty = tid >> 4;
    int mb = blockIdx.x * 64, nb = blockIdx.y * 64;
    int lr = tid >> 2, lk = (tid & 3) * 4;
    float acc[4][4] = {};
    for (int k0 = 0; k0 < 512; k0 += 16) {
        int kg = k0 + lk;
        float4 a;
        if (kg < 256) {
            float4 d4 = *(const float4*)(deltas + (size_t)(mb + lr) * 256 + kg);
            a.x = expf(-fmaxf(d4.x * Wtdx[(size_t)(kg + 0) * 257] + btdx[kg + 0], 0.0f));
            a.y = expf(-fmaxf(d4.y * Wtdx[(size_t)(kg + 1) * 257] + btdx[kg + 1], 0.0f));
            a.z = expf(-fmaxf(d4.z * Wtdx[(size_t)(kg + 2) * 257] + btdx[kg + 2], 0.0f));
            a.w = expf(-fmaxf(d4.w * Wtdx[(size_t)(kg + 3) * 257] + btdx[kg + 3], 0.0f));
        } else {
            a = *(const float4*)(masks + (size_t)(mb + lr) * 256 + (kg - 256));
        }
        float4 b = *(const float4*)(Wc + (size_t)(nb + lr) * 512 + kg);
        As[lk + 0][lr] = a.x; As[lk + 1][lr] = a.y; As[lk + 2][lr] = a.z; As[lk + 3][lr] = a.w;
        Bs[lk + 0][lr] = b.x; Bs[lk + 1][lr] = b.y; Bs[lk + 2][lr] = b.z; Bs[lk + 3][lr] = b.w;
        __syncthreads();
#pragma unroll
        for (int kk = 0; kk < 16; kk++) {
            float av[4], bv[4];
#pragma unroll
            for (int i = 0; i < 4; i++) av[i] = As[kk][ty * 4 + i];
#pragma unroll
            for (int j = 0; j < 4; j++) bv[j] = Bs[kk][tx * 4 + j];
#pragma unroll
            for (int i = 0; i < 4; i++)
#pragma unroll
                for (int j = 0; j < 4; j++) acc[i][j] = fmaf(av[i], bv[j], acc[i][j]);
        }
        __syncthreads();
    }
#pragma unroll
    for (int i = 0; i < 4; i++) {
        int r = mb + ty * 4 + i;
#pragma unroll
        for (int j = 0; j < 4; j++) {
            int n = nb + tx * 4 + j;
            al[(size_t)r * 256 + n] = f2bf(sigm(acc[i][j] + bc[n]));
        }
    }
}

// ---------------- persistent kernel ----------------

__global__ __launch_bounds__(256, 1) void k_persist(const float* __restrict__ values,
                                                    const float* __restrict__ masks,
                                                    const float* __restrict__ b_hist,
                                                    const float* __restrict__ b_feat,
                                                    float* __restrict__ out,
                                                    unsigned char* __restrict__ wsb) {
    ushortT* hd[2] = { (ushortT*)(wsb + OB_HD0), (ushortT*)(wsb + OB_HD1) };
    ushortT* xcb = (ushortT*)(wsb + OB_XCB);
    ushortT* ccb = (ushortT*)(wsb + OB_CCB);
    float* num2 = (float*)(wsb + OB_NUM2);
    const float* den = (const float*)(wsb + OB_DEN);
    const float* biasp = (const float*)(wsb + OB_BIASP);
    const ushortT* Ba = (const ushortT*)(wsb + OB_BA);
    const ushortT* Bb = (const ushortT*)(wsb + OB_BB);
    const ushortT* Bc = (const ushortT*)(wsb + OB_BC);
    const ushortT* mt = (const ushortT*)(wsb + OB_MT);
    const ushortT* gh = (const ushortT*)(wsb + OB_GH);
    const ushortT* al = (const ushortT*)(wsb + OB_AL);

    __shared__ ushortT ldsBc[32 * 1032];   // 66048 B
    __shared__ ushortT ldsBa[16 * 520];    // 16640 B
    __shared__ ushortT ldsBb[16 * 264];    //  8448 B
    __shared__ float scr[4 * 16 * 36];     //  9216 B: per-wave gate scratch
    __shared__ float lossSlots[8];

    const int wg = blockIdx.x, tid = threadIdx.x;
    const int wave = tid >> 6, lane = tid & 63, quad = lane >> 4, l16 = lane & 15;
    const int d = wg & 3;                  // row domain (batch rows d*64..+63)
    const int k = wg >> 2;                 // 0..63 within domain

    unsigned* flgs = (unsigned*)(wsb + OB_FLG);
    unsigned* fA = flgs + d * 64;          // slots 0..15 used
    unsigned* fB = flgs + 256 + d * 64;    // slots 0..15 used
    unsigned* fC = flgs + 512 + d * 64;    // slots 0..63 used
    unsigned* cntF = flgs + 768;

    // ---- load LDS weight slices (once) ----
    {
        int n0 = k * 32;                              // phase C: 32 packed rows
        for (int i = tid; i < 4096; i += 256) {
            int r = i >> 7, c = i & 127;
            *(short8*)&ldsBc[r * 1032 + c * 8] = *(const short8*)&Bc[(size_t)(n0 + r) * 1024 + c * 8];
        }
        if (wg < 64) {                                // A/B workers: k<16
            int nA = k * 16;
            for (int i = tid; i < 1024; i += 256) {
                int r = i >> 6, c = i & 63;
                *(short8*)&ldsBa[r * 520 + c * 8] = *(const short8*)&Ba[(size_t)(nA + r) * 512 + c * 8];
            }
            for (int i = tid; i < 512; i += 256) {
                int r = i >> 5, c = i & 31;
                *(short8*)&ldsBb[r * 264 + c * 8] = *(const short8*)&Bb[(size_t)(nA + r) * 256 + c * 8];
            }
        }
        __syncthreads();
    }

    // t-invariant mappings
    const int r0C = d * 64 + wave * 16;               // this wave's 16 rows
    const int lb0 = l16 * 1032 + quad * 8;
    const int lb1 = (16 + l16) * 1032 + quad * 8;
    const float bp0 = biasp[k * 32 + l16];
    const float bp1 = biasp[k * 32 + 16 + l16];
    const int rowl = lane >> 2, q4 = lane & 3;
    const int bbE = r0C + rowl;
    const int j0E = k * 8 + q4, j1E = j0E + 4;
    float creg0 = 0.f, creg1 = 0.f;

    const int nbA = k * 16;                            // A/B col block (k<16)
    const int nA_ = nbA + l16;

#pragma unroll 1
    for (int t = 0; t < T_; ++t) {
        const ushortT* hdA = hd[t & 1];
        ushortT* hdW = hd[(t + 1) & 1];

        if (t) bar_wait(fC, 64, (unsigned)t);          // hd[t] ready (domain-local)

        float xhv[4], xr[4], mr[4];

        // ---- phase A (A/B workers): x_h = hdec @ W_hist.T ----
        if (wg < 64) {
            f32x4 acc = {0.f, 0.f, 0.f, 0.f};
            const ushortT* aBase = hdA + (size_t)(r0C + l16) * 512 + quad * 8;
#pragma unroll 8
            for (int kc = 0; kc < 16; ++kc) {
                short8 a = *(const short8*)(aBase + kc * 32);
                short8 b = *(const short8*)&ldsBa[l16 * 520 + kc * 32 + quad * 8];
                acc = __builtin_amdgcn_mfma_f32_16x16x32_bf16(a, b, acc, 0, 0, 0);
            }
            float bh = b_hist[nA_];
            float ls = 0.f;
#pragma unroll
            for (int r4 = 0; r4 < 4; ++r4) {
                int r = r0C + quad * 4 + r4;
                float v = acc[r4] + bh;
                xhv[r4] = v;
                size_t idx = ((size_t)r * T_ + t) * 256 + nA_;
                xr[r4] = values[idx]; mr[r4] = masks[idx];
                st_bf16_wt(&xcb[r * 256 + nA_], f2bf(mr[r4] * xr[r4] + (1.f - mr[r4]) * v));
                ls += fabsf(v - xr[r4]) * mr[r4];
            }
            for (int off = 32; off; off >>= 1) ls += __shfl_down(ls, off);
            if (lane == 0) lossSlots[wave] = ls;
            bar_arrive(&fA[k], (unsigned)(t + 1));
        }

        // ---- phase C seg(mt) + seg(hd): hoisted, no dependency on A/B ----
        f32x4 acc0 = {0.f, 0.f, 0.f, 0.f}, acc1 = {0.f, 0.f, 0.f, 0.f};
        {
            const ushortT* ap = mt + (size_t)t * 65536 + (size_t)(r0C + l16) * 256 + quad * 8;
#pragma unroll
            for (int kc = 0; kc < 8; ++kc) {
                short8 a  = *(const short8*)(ap + kc * 32);
                short8 b0 = *(const short8*)&ldsBc[lb0 + 256 + kc * 32];
                short8 b1 = *(const short8*)&ldsBc[lb1 + 256 + kc * 32];
                acc0 = __builtin_amdgcn_mfma_f32_16x16x32_bf16(a, b0, acc0, 0, 0, 0);
                acc1 = __builtin_amdgcn_mfma_f32_16x16x32_bf16(a, b1, acc1, 0, 0, 0);
            }
        }
        {
            const ushortT* ap = hdA + (size_t)(r0C + l16) * 512 + quad * 8;
#pragma unroll 8
            for (int kc = 0; kc < 16; ++kc) {
                short8 a  = *(const short8*)(ap + kc * 32);
                short8 b0 = *(const short8*)&ldsBc[lb0 + 512 + kc * 32];
                short8 b1 = *(const short8*)&ldsBc[lb1 + 512 + kc * 32];
                acc0 = __builtin_amdgcn_mfma_f32_16x16x32_bf16(a, b0, acc0, 0, 0, 0);
                acc1 = __builtin_amdgcn_mfma_f32_16x16x32_bf16(a, b1, acc1, 0, 0, 0);
            }
        }

        // ---- phase B (A/B workers): z_h = x_c @ Wf.T; c_h, c_c, losses ----
        if (wg < 64) {
            bar_wait(fA, 16, (unsigned)(t + 1));
            f32x4 acc = {0.f, 0.f, 0.f, 0.f};
            const ushortT* aBase = xcb + (size_t)(r0C + l16) * 256 + quad * 8;
#pragma unroll
            for (int kc = 0; kc < 8; ++kc) {
                short8 a = *(const short8*)(aBase + kc * 32);
                short8 b = *(const short8*)&ldsBb[l16 * 264 + kc * 32 + quad * 8];
                acc = __builtin_amdgcn_mfma_f32_16x16x32_bf16(a, b, acc, 0, 0, 0);
            }
            float bfv = b_feat[nA_];
            float ls = 0.f;
#pragma unroll
            for (int r4 = 0; r4 < 4; ++r4) {
                int r = r0C + quad * 4 + r4;
                float z = fmaxf(acc[r4] + bfv, 0.f);
                size_t idx = ((size_t)r * T_ + t) * 256 + nA_;
                float a_ = bf2f(al[idx]);
                float ch = a_ * z + (1.f - a_) * xhv[r4];
                float ccv = mr[r4] * xr[r4] + (1.f - mr[r4]) * ch;
                out[idx] = ccv;                        // imputed[:,t,:] == c_c
                st_bf16_wt(&ccb[r * 256 + nA_], f2bf(ccv));
                ls += (fabsf(z - xr[r4]) + fabsf(ch - xr[r4])) * mr[r4];
            }
            for (int off = 32; off; off >>= 1) ls += __shfl_down(ls, off);
            if (lane == 0) lossSlots[4 + wave] = ls;
            __syncthreads();
            if (tid == 0) {
                float s = 0.f;
                for (int i = 0; i < 8; ++i) s += lossSlots[i];
                st_f32_wt(&num2[t * 64 + wg], s);
            }
            bar_arrive(&fB[k], (unsigned)(t + 1));
        }

        // ---- phase C seg(ccb) + LSTM epilogue (all wgs) ----
        bar_wait(fB, 16, (unsigned)(t + 1));
        {
            const ushortT* ap = ccb + (size_t)(r0C + l16) * 256 + quad * 8;
#pragma unroll
            for (int kc = 0; kc < 8; ++kc) {
                short8 a  = *(const short8*)(ap + kc * 32);
                short8 b0 = *(const short8*)&ldsBc[lb0 + kc * 32];
                short8 b1 = *(const short8*)&ldsBc[lb1 + kc * 32];
                acc0 = __builtin_amdgcn_mfma_f32_16x16x32_bf16(a, b0, acc0, 0, 0, 0);
                acc1 = __builtin_amdgcn_mfma_f32_16x16x32_bf16(a, b1, acc1, 0, 0, 0);
            }
        }
        {
            float* ms = scr + wave * (16 * 36);
#pragma unroll
            for (int r4 = 0; r4 < 4; ++r4) {
                ms[(quad * 4 + r4) * 36 + l16]      = acc0[r4] + bp0;
                ms[(quad * 4 + r4) * 36 + 16 + l16] = acc1[r4] + bp1;
            }
            const float* g0 = &ms[rowl * 36 + q4 * 4];
            const float* g1 = &ms[rowl * 36 + 16 + q4 * 4];
            float cn0 = sigm(g0[1]) * creg0 + sigm(g0[0]) * tanhf(g0[2]);
            float hn0 = sigm(g0[3]) * tanhf(cn0);
            float cn1 = sigm(g1[1]) * creg1 + sigm(g1[0]) * tanhf(g1[2]);
            float hn1 = sigm(g1[3]) * tanhf(cn1);
            creg0 = cn0; creg1 = cn1;
            if (t < T_ - 1) {
                float gv0 = bf2f(gh[((size_t)bbE * T_ + t + 1) * 512 + j0E]);
                float gv1 = bf2f(gh[((size_t)bbE * T_ + t + 1) * 512 + j1E]);
                st_bf16_wt(&hdW[(size_t)bbE * 512 + j0E], f2bf(hn0 * gv0));
                st_bf16_wt(&hdW[(size_t)bbE * 512 + j1E], f2bf(hn1 * gv1));
                bar_arrive(&fC[k], (unsigned)(t + 1));
            } else {
                out[6553600 + (size_t)bbE * 512 + j0E] = hn0;
                out[6553600 + (size_t)bbE * 512 + j1E] = hn1;
            }
        }
    }

    // ---- finalize: one-time global sync, then loss reduction by wg 0 ----
    if (tid == 0)
        __hip_atomic_fetch_add(cntF, 1u, __ATOMIC_RELAXED, __HIP_MEMORY_SCOPE_AGENT);
    if (wg == 0) {
        if (tid == 0) {
            while (__hip_atomic_load(cntF, __ATOMIC_RELAXED, __HIP_MEMORY_SCOPE_AGENT) < 256u)
                __builtin_amdgcn_s_sleep(2);
            __builtin_amdgcn_fence(__ATOMIC_ACQUIRE, "agent");
        }
        __syncthreads();
        float v = 0.f;
        if (tid < T_) {
            float s = 0.f;
            for (int w = 0; w < 64; ++w) s += num2[tid * 64 + w];
            v = s / (den[tid] + 1e-9f);
        }
        scr[tid] = v;
        __syncthreads();
        for (int s = 128; s > 0; s >>= 1) { if (tid < s) scr[tid] += scr[tid + s]; __syncthreads(); }
        if (tid == 0) out[6684672] = scr[0] / 300.0f;
    }
}

extern "C" void kernel_launch(void* const* d_in, const int* in_sizes, int n_in,
                              void* d_out, int out_size, void* d_ws, size_t ws_size,
                              hipStream_t stream) {
    (void)in_sizes; (void)n_in; (void)out_size; (void)ws_size;
    const float* values = (const float*)d_in[0];
    const float* masks  = (const float*)d_in[1];
    const float* deltas = (const float*)d_in[2];
    const float* W_td_h = (const float*)d_in[3];
    const float* b_td_h = (const float*)d_in[4];
    const float* W_td_x = (const float*)d_in[5];
    const float* b_td_x = (const float*)d_in[6];
    const float* W_hist = (const float*)d_in[7];
    const float* b_hist = (const float*)d_in[8];
    const float* W_feat = (const float*)d_in[9];
    const float* b_feat = (const float*)d_in[10];
    const float* W_comb = (const float*)d_in[11];
    const float* b_comb = (const float*)d_in[12];
    const float* W_ih   = (const float*)d_in[13];
    const float* W_hh   = (const float*)d_in[14];
    const float* b_ih   = (const float*)d_in[15];
    const float* b_hh   = (const float*)d_in[16];

    unsigned char* wsb = (unsigned char*)d_ws;
    float* out = (float*)d_out;

    k_init2<<<256, 256, 0, stream>>>(wsb);
    k_prep2<<<2048, 256, 0, stream>>>(W_ih, W_hh, b_ih, b_hh, W_hist, W_feat, wsb);
    k_den<<<100, 256, 0, stream>>>(masks, wsb);
    k_maskt<<<6400, 256, 0, stream>>>(masks, wsb);
    k_gamma_h<<<dim3(400, 8), 256, 0, stream>>>(deltas, W_td_h, b_td_h, wsb);
    k_alpha<<<dim3(400, 4), 256, 0, stream>>>(deltas, masks, W_td_x, b_td_x, W_comb, b_comb, wsb);
    k_persist<<<256, 256, 0, stream>>>(values, masks, b_hist, b_feat, out, wsb);
}